// Round 8
// baseline (209.882 us; speedup 1.0000x reference)
//
#include <hip/hip_runtime.h>

#define BLK   256
#define NSAMP 4
#define REG   1480          // dwords per sample LDS region
// per-sample region map (dword offsets):
//  IMG:  halfwords [0..783] = dwords [0..391] (bf16 packed; dead after conv1)
//  P2:   dw [0..149]   (5x5x6 fp32, c*25+pos)   -- aliases dead IMG
//  P3:   dw [152..178] (3x3x3 fp32, c*9+pos)    -- aliases dead IMG
//  W:    dw [392..1203] (811 hypernet weights, fp32)
//  P1:   halfwords [2408..2953] (3ch * 13rows * stride14, bf16 packed)
#define OFF_P2   0
#define OFF_P3   152
#define OFF_W    392
#define HW_P1    2408       // halfword offset of P1 within region

// weight sub-offsets within OFF_W (SPLITS):
//  w1 0..27 (co*9+pp), b1 27..30, w2 30..192 (co*27+pp*3+ci), b2 192..198,
//  w3 198..360 (co*54+pp*6+ci), b3 360..363, w4 363..795 (co*27+pp*3+ci), b4 795..811

typedef float f32x2 __attribute__((ext_vector_type(2)));  // -> v_pk_*_f32

__device__ __forceinline__ float bf2f(unsigned short u) {
    return __uint_as_float(((unsigned int)u) << 16);
}
__device__ __forceinline__ unsigned short f2bf(float f) {
    unsigned int x = __float_as_uint(f);
    return (unsigned short)((x + 0x7fffu + ((x >> 16) & 1u)) >> 16);   // RNE
}
// wave-internal LDS ordering fence (DS retire + compiler barrier)
__device__ __forceinline__ void wsync() {
    __builtin_amdgcn_wave_barrier();
    __asm__ volatile("s_waitcnt lgkmcnt(0)" ::: "memory");
    __builtin_amdgcn_wave_barrier();
}

// Runtime dtype detection (proven R2/R4/R5): probe EVEN halfwords.
__device__ __forceinline__ bool is_bf16(const void* p, int elems) {
    const unsigned short* h = (const unsigned short*)p;
    int n = elems; if (n > 32) n = 32;
    int nz = 0, ok = 0;
    for (int i = 0; i < n; i += 2) {
        unsigned short u = h[i];
        if (u == 0) continue;
        ++nz;
        unsigned int e = (u >> 7) & 255u;
        if (e >= 100u && e <= 141u) ++ok;
    }
    if (nz < 4) return true;
    return 4 * ok >= 3 * nz;
}

// bound=5 (VGPR cap 102): bound=6 (cap 85) spilled in R6 (WRITE 1->90MB).
// LDS 23.7KB is the occupancy limiter -> up to 6 blocks/CU if VGPR alloc <= 85.
__global__ __launch_bounds__(BLK, 5)
void dyncnn4_kernel(const void* __restrict__ image,   // [784, B]
                    const void* __restrict__ state,   // [B, 16]
                    const void* __restrict__ W1, const void* __restrict__ b1,
                    const void* __restrict__ W2, const void* __restrict__ b2,
                    const void* __restrict__ W3, const void* __restrict__ b3,
                    void* __restrict__ out,           // [B,16]
                    int B, int nswz)
{
    __shared__ float SH[NSAMP * REG];     // 23680 B
    __shared__ float s_st[NSAMP][16];
    __shared__ float s_h1[NSAMP][16];
    __shared__ float s_h2[NSAMP][16];

    const int t    = threadIdx.x;
    const int wv   = t >> 6;
    const int lane = t & 63;

    const bool im_bf = is_bf16(image, 784 * B);
    const bool st_bf = is_bf16(state, 16 * B);
    const bool w1_bf = is_bf16(W1, 256);
    const bool b1_bf = is_bf16(b1, 16);
    const bool w2_bf = is_bf16(W2, 256);
    const bool b2_bf = is_bf16(b2, 16);
    const bool w3_bf = is_bf16(W3, 12976);
    const bool b3_bf = is_bf16(b3, 811);
    const bool out_bf = im_bf && st_bf && w1_bf && w2_bf && w3_bf;

    int p = blockIdx.x;
    int l = (nswz > 0) ? ((p & 7) * nswz + (p >> 3)) : p;
    const int b0 = l * NSAMP;

    unsigned short* su = (unsigned short*)SH;   // halfword view

    // ==== phase 0: wave0 = MLP, waves1-3 = image staging (no block barrier) ====
    if (wv == 0) {
        int s = lane >> 4, j = lane & 15;
        int gi = (b0 + s) * 16 + j;
        s_st[s][j] = st_bf ? bf2f(((const unsigned short*)state)[gi])
                           : ((const float*)state)[gi];
        wsync();
        float acc = b1_bf ? bf2f(((const unsigned short*)b1)[j])
                          : ((const float*)b1)[j];
#pragma unroll
        for (int k = 0; k < 16; ++k) {
            float w = w1_bf ? bf2f(((const unsigned short*)W1)[k * 16 + j])
                            : ((const float*)W1)[k * 16 + j];
            acc += s_st[s][k] * w;
        }
        s_h1[s][j] = fmaxf(acc, 0.f);
        wsync();
        acc = b2_bf ? bf2f(((const unsigned short*)b2)[j])
                    : ((const float*)b2)[j];
#pragma unroll
        for (int k = 0; k < 16; ++k) {
            float w = w2_bf ? bf2f(((const unsigned short*)W2)[k * 16 + j])
                            : ((const float*)W2)[k * 16 + j];
            acc += s_h1[s][k] * w;
        }
        s_h2[s][j] = fmaxf(acc, 0.f);
    } else {
        if (im_bf) {
            const unsigned short* im = (const unsigned short*)image;
            for (int pix = t - 64; pix < 784; pix += 192) {
                const uint2 v = *(const uint2*)(im + pix * B + b0);
                su[0 * 2 * REG + pix] = (unsigned short)(v.x);
                su[1 * 2 * REG + pix] = (unsigned short)(v.x >> 16);
                su[2 * 2 * REG + pix] = (unsigned short)(v.y);
                su[3 * 2 * REG + pix] = (unsigned short)(v.y >> 16);
            }
        } else {
            const float* im = (const float*)image;
            for (int pix = t - 64; pix < 784; pix += 192) {
                const float4 v = *(const float4*)(im + pix * B + b0);
                su[0 * 2 * REG + pix] = f2bf(v.x);
                su[1 * 2 * REG + pix] = f2bf(v.y);
                su[2 * 2 * REG + pix] = f2bf(v.z);
                su[3 * 2 * REG + pix] = f2bf(v.w);
            }
        }
    }
    __syncthreads();   // barrier #1: image staged + h2 ready

    // ==== head: w = h2 @ W3 + b3, packed pairs (samples 0,1)/(2,3) ====
    {
        f32x2 hA[16], hB[16];
#pragma unroll
        for (int k = 0; k < 16; ++k) {
            hA[k] = (f32x2){s_h2[0][k], s_h2[1][k]};
            hB[k] = (f32x2){s_h2[2][k], s_h2[3][k]};
        }
        for (int j = t; j < 811; j += BLK) {
            float bb = b3_bf ? bf2f(((const unsigned short*)b3)[j])
                             : ((const float*)b3)[j];
            f32x2 aA = (f32x2){bb, bb}, aB = (f32x2){bb, bb};
            if (w3_bf) {
                const unsigned short* q = (const unsigned short*)W3 + j;
#pragma unroll
                for (int k = 0; k < 16; ++k) {
                    float w = bf2f(q[k * 811]);
                    f32x2 wf = (f32x2){w, w};
                    aA += hA[k] * wf; aB += hB[k] * wf;
                }
            } else {
                const float* q = (const float*)W3 + j;
#pragma unroll
                for (int k = 0; k < 16; ++k) {
                    float w = q[k * 811];
                    f32x2 wf = (f32x2){w, w};
                    aA += hA[k] * wf; aB += hB[k] * wf;
                }
            }
            SH[0 * REG + OFF_W + j] = aA.x;
            SH[1 * REG + OFF_W + j] = aA.y;
            SH[2 * REG + OFF_W + j] = aB.x;
            SH[3 * REG + OFF_W + j] = aB.y;
        }
    }
    __syncthreads();   // barrier #2: weights ready — conv phase is wave-local

    // ==== per-wave CNN: wave wv owns sample b0+wv ====
    const int sb = wv * REG;

    // ---- conv1 (1->3, 28x28 -> fused pool -> 13x13x3 bf16), packed ----
    {
        float wc[27], cb[3];
#pragma unroll
        for (int i = 0; i < 27; ++i) wc[i] = SH[sb + OFF_W + i];
#pragma unroll
        for (int c = 0; c < 3; ++c) cb[c] = SH[sb + OFF_W + 27 + c];
        const unsigned* suw = (const unsigned*)&SH[sb];  // 2 pixels per dword
#pragma unroll
        for (int it = 0; it < 3; ++it) {
            int pix = lane + it * 64;
            if (pix < 169) {
                int py = pix / 13, px = pix - py * 13;
                int iy = 2 * py;
                f32x2 e[4][3];   // overlapping column pairs per row
#pragma unroll
                for (int dy = 0; dy < 4; ++dy) {
                    int r = (iy + dy) * 14 + px;
                    unsigned d0 = suw[r], d1 = suw[r + 1];
                    float p0 = __uint_as_float(d0 << 16);
                    float p1 = __uint_as_float(d0 & 0xffff0000u);
                    float p2 = __uint_as_float(d1 << 16);
                    float p3 = __uint_as_float(d1 & 0xffff0000u);
                    e[dy][0] = (f32x2){p0, p1};
                    e[dy][1] = (f32x2){p1, p2};
                    e[dy][2] = (f32x2){p2, p3};
                }
                unsigned short* op = &su[sb * 2 + HW_P1 + py * 14 + px];
#pragma unroll
                for (int c = 0; c < 3; ++c) {
                    f32x2 A = (f32x2){0.f, 0.f};   // (a00, a01)
                    f32x2 Bv = (f32x2){0.f, 0.f};  // (a10, a11)
#pragma unroll
                    for (int ky = 0; ky < 3; ++ky)
#pragma unroll
                        for (int kx = 0; kx < 3; ++kx) {
                            float w = wc[c * 9 + ky * 3 + kx];
                            f32x2 wf = (f32x2){w, w};
                            A  += e[ky][kx] * wf;
                            Bv += e[ky + 1][kx] * wf;
                        }
                    float m = fmaxf(fmaxf(A.x, A.y), fmaxf(Bv.x, Bv.y));
                    op[c * 182] = f2bf(fmaxf(m + cb[c], 0.f));
                }
            }
        }
    }
    wsync();

    // ---- conv2 (3->6, 13x13 -> fused pool -> 5x5x6 fp32), ci-outer packed ----
    {
        int g = lane >> 5, q = lane & 31;
        if (q < 25) {
            int py = q / 5, px = q - py * 5;
            const unsigned* p1w = (const unsigned*)&SH[sb + 1204];  // P1 dwords
            f32x2 accA[3], accB[3];
#pragma unroll
            for (int it = 0; it < 3; ++it) {
                accA[it] = (f32x2){0.f, 0.f};
                accB[it] = (f32x2){0.f, 0.f};
            }
#pragma unroll
            for (int ci = 0; ci < 3; ++ci) {
                f32x2 e[4][3];
#pragma unroll
                for (int dy = 0; dy < 4; ++dy) {
                    int r = ci * 91 + (2 * py + dy) * 7 + px;
                    unsigned d0 = p1w[r], d1 = p1w[r + 1];
                    float p0 = __uint_as_float(d0 << 16);
                    float p1 = __uint_as_float(d0 & 0xffff0000u);
                    float p2 = __uint_as_float(d1 << 16);
                    float p3 = __uint_as_float(d1 & 0xffff0000u);
                    e[dy][0] = (f32x2){p0, p1};
                    e[dy][1] = (f32x2){p1, p2};
                    e[dy][2] = (f32x2){p2, p3};
                }
#pragma unroll
                for (int it = 0; it < 3; ++it) {
                    int c = it * 2 + g;
                    const int wo = sb + OFF_W + 30 + c * 27 + ci;
#pragma unroll
                    for (int ky = 0; ky < 3; ++ky)
#pragma unroll
                        for (int kx = 0; kx < 3; ++kx) {
                            float w = SH[wo + (ky * 3 + kx) * 3];
                            f32x2 wf = (f32x2){w, w};
                            accA[it] += e[ky][kx] * wf;
                            accB[it] += e[ky + 1][kx] * wf;
                        }
                }
            }
#pragma unroll
            for (int it = 0; it < 3; ++it) {
                int c = it * 2 + g;
                float m = fmaxf(fmaxf(accA[it].x, accA[it].y),
                                fmaxf(accB[it].x, accB[it].y));
                SH[sb + OFF_P2 + c * 25 + q] = fmaxf(m + SH[sb + OFF_W + 192 + c], 0.f);
            }
        }
    }
    wsync();

    // ---- conv3 (6->3, 5x5 -> 3x3) + relu, 54-lane split over ci halves ----
    {
        float acc = 0.f;
        int pq = lane % 27;            // 0..26: c*9 + pos
        int half = lane / 27;          // 0,1 active; lane>=54 idle
        int c = pq / 9, pos = pq - c * 9;
        int py = pos / 3, px = pos - py * 3;
        if (lane < 54) {
            const int wo = sb + OFF_W + 198 + c * 54;
            const int cb3 = half * 3;
#pragma unroll
            for (int ky = 0; ky < 3; ++ky)
#pragma unroll
                for (int kx = 0; kx < 3; ++kx)
#pragma unroll
                    for (int ci = 0; ci < 3; ++ci)
                        acc += SH[sb + OFF_P2 + (cb3 + ci) * 25 + (py + ky) * 5 + px + kx] *
                               SH[wo + (ky * 3 + kx) * 6 + cb3 + ci];
        }
        float other = __shfl(acc, (lane + 27) & 63);
        if (lane < 27)
            SH[sb + OFF_P3 + pq] = fmaxf(acc + other + SH[sb + OFF_W + 360 + c], 0.f);
    }
    wsync();

    // ---- conv4 (3->16) + bias + residual -> out, 32-lane split over pp ----
    // P3 channel-major (ci*9+pp), w4 spatial-major (pp*3+ci).
    {
        float acc = 0.f;
        int os = lane & 15, h = (lane >> 4) & 1;
        if (lane < 32) {
            const int wo = sb + OFF_W + 363 + os * 27;
            int p0 = h ? 4 : 0, p1 = h ? 9 : 4;
            for (int pp = p0; pp < p1; ++pp)
#pragma unroll
                for (int ci = 0; ci < 3; ++ci)
                    acc += SH[sb + OFF_P3 + ci * 9 + pp] * SH[wo + pp * 3 + ci];
        }
        float other = __shfl(acc, (lane + 16) & 63);
        if (lane < 16) {
            float tot = acc + other + SH[sb + OFF_W + 795 + os] + s_st[wv][os];
            int gi = (b0 + wv) * 16 + os;
            if (out_bf) ((unsigned short*)out)[gi] = f2bf(tot);
            else        ((float*)out)[gi] = tot;
        }
    }
}

extern "C" void kernel_launch(void* const* d_in, const int* in_sizes, int n_in,
                              void* d_out, int out_size, void* d_ws, size_t ws_size,
                              hipStream_t stream) {
    (void)d_ws; (void)ws_size; (void)n_in; (void)out_size;
    int B = in_sizes[1] / 16;              // 16384
    int nblocks = B / NSAMP;               // 4096
    int nswz = (nblocks % 8 == 0) ? (nblocks / 8) : 0;

    dyncnn4_kernel<<<nblocks, BLK, 0, stream>>>(
        d_in[0], d_in[1], d_in[2], d_in[3], d_in[4], d_in[5], d_in[6], d_in[7],
        d_out, B, nswz);
}

// Round 9
// 163.318 us; speedup vs baseline: 1.2851x; 1.2851x over previous
//
#include <hip/hip_runtime.h>

#define BLK   256
#define NSAMP 4
#define REG   1072          // dwords per sample LDS region (4288 B, 16B-aligned)
// per-sample region map:
//  IMG:  halfwords [0..783] = dw [0..391] (bf16; dead after conv1)
//  P2:   dw [0..149]   (5x5x6 fp32, c*25+pos)   -- aliases dead IMG
//  P3:   dw [152..178] (3x3x3 fp32, c*9+pos)    -- aliases dead IMG
//  W:    halfwords [784..1594] = dw [392..797] (811 hypernet weights, bf16)
//  P1:   halfwords [1596..2141] = dw [798..1070] (3ch * 13rows * stride14, bf16)
#define OFF_P2   0          // dw
#define OFF_P3   152        // dw
#define HWW      784        // halfword offset of W
#define HW_P1    1596       // halfword offset of P1
#define DW_P1    798        // dword offset of P1

// weight sub-offsets within W (SPLITS):
//  w1 0..27 (co*9+pp), b1 27..30, w2 30..192 (co*27+pp*3+ci), b2 192..198,
//  w3 198..360 (co*54+pp*6+ci), b3 360..363, w4 363..795 (co*27+pp*3+ci), b4 795..811

__device__ __forceinline__ float bf2f(unsigned short u) {
    return __uint_as_float(((unsigned int)u) << 16);
}
__device__ __forceinline__ unsigned short f2bf(float f) {
    unsigned int x = __float_as_uint(f);
    return (unsigned short)((x + 0x7fffu + ((x >> 16) & 1u)) >> 16);   // RNE
}
// wave-internal LDS ordering fence (DS retire + compiler barrier)
__device__ __forceinline__ void wsync() {
    __builtin_amdgcn_wave_barrier();
    __asm__ volatile("s_waitcnt lgkmcnt(0)" ::: "memory");
    __builtin_amdgcn_wave_barrier();
}

// Runtime dtype detection (proven R2/R4/R5): probe EVEN halfwords.
__device__ __forceinline__ bool is_bf16(const void* p, int elems) {
    const unsigned short* h = (const unsigned short*)p;
    int n = elems; if (n > 32) n = 32;
    int nz = 0, ok = 0;
    for (int i = 0; i < n; i += 2) {
        unsigned short u = h[i];
        if (u == 0) continue;
        ++nz;
        unsigned int e = (u >> 7) & 255u;
        if (e >= 100u && e <= 141u) ++ok;
    }
    if (nz < 4) return true;
    return 4 * ok >= 3 * nz;
}

// bound=5 (VGPR cap 102): proven no-spill (R7, 48 VGPR). LDS ~17.9KB now the
// only limiter -> up to 8 blocks/CU (32 waves). NO ext_vector arrays (R8: the
// compiler lowered f32x2 arrays to scratch -> 61 MB WRITE_SIZE, 1.6x regression).
__global__ __launch_bounds__(BLK, 5)
void dyncnn4_kernel(const void* __restrict__ image,   // [784, B]
                    const void* __restrict__ state,   // [B, 16]
                    const void* __restrict__ W1, const void* __restrict__ b1,
                    const void* __restrict__ W2, const void* __restrict__ b2,
                    const void* __restrict__ W3, const void* __restrict__ b3,
                    void* __restrict__ out,           // [B,16]
                    int B, int nswz)
{
    __shared__ float SH[NSAMP * REG];     // 17152 B
    __shared__ float s_st[NSAMP][16];
    __shared__ float s_h1[NSAMP][16];
    __shared__ float s_h2[NSAMP][16];

    const int t    = threadIdx.x;
    const int wv   = t >> 6;
    const int lane = t & 63;

    const bool im_bf = is_bf16(image, 784 * B);
    const bool st_bf = is_bf16(state, 16 * B);
    const bool w1_bf = is_bf16(W1, 256);
    const bool b1_bf = is_bf16(b1, 16);
    const bool w2_bf = is_bf16(W2, 256);
    const bool b2_bf = is_bf16(b2, 16);
    const bool w3_bf = is_bf16(W3, 12976);
    const bool b3_bf = is_bf16(b3, 811);
    const bool out_bf = im_bf && st_bf && w1_bf && w2_bf && w3_bf;

    int p = blockIdx.x;
    int l = (nswz > 0) ? ((p & 7) * nswz + (p >> 3)) : p;
    const int b0 = l * NSAMP;

    unsigned short* su = (unsigned short*)SH;   // halfword view

    // ==== phase 0: wave0 = MLP, waves1-3 = image staging (no block barrier) ====
    if (wv == 0) {
        int s = lane >> 4, j = lane & 15;
        int gi = (b0 + s) * 16 + j;
        s_st[s][j] = st_bf ? bf2f(((const unsigned short*)state)[gi])
                           : ((const float*)state)[gi];
        wsync();
        float acc = b1_bf ? bf2f(((const unsigned short*)b1)[j])
                          : ((const float*)b1)[j];
#pragma unroll
        for (int k = 0; k < 16; ++k) {
            float w = w1_bf ? bf2f(((const unsigned short*)W1)[k * 16 + j])
                            : ((const float*)W1)[k * 16 + j];
            acc += s_st[s][k] * w;
        }
        s_h1[s][j] = fmaxf(acc, 0.f);
        wsync();
        acc = b2_bf ? bf2f(((const unsigned short*)b2)[j])
                    : ((const float*)b2)[j];
#pragma unroll
        for (int k = 0; k < 16; ++k) {
            float w = w2_bf ? bf2f(((const unsigned short*)W2)[k * 16 + j])
                            : ((const float*)W2)[k * 16 + j];
            acc += s_h1[s][k] * w;
        }
        s_h2[s][j] = fmaxf(acc, 0.f);
    } else {
        if (im_bf) {
            const unsigned short* im = (const unsigned short*)image;
            for (int pix = t - 64; pix < 784; pix += 192) {
                const uint2 v = *(const uint2*)(im + pix * B + b0);
                su[0 * 2 * REG + pix] = (unsigned short)(v.x);
                su[1 * 2 * REG + pix] = (unsigned short)(v.x >> 16);
                su[2 * 2 * REG + pix] = (unsigned short)(v.y);
                su[3 * 2 * REG + pix] = (unsigned short)(v.y >> 16);
            }
        } else {
            const float* im = (const float*)image;
            for (int pix = t - 64; pix < 784; pix += 192) {
                const float4 v = *(const float4*)(im + pix * B + b0);
                su[0 * 2 * REG + pix] = f2bf(v.x);
                su[1 * 2 * REG + pix] = f2bf(v.y);
                su[2 * 2 * REG + pix] = f2bf(v.z);
                su[3 * 2 * REG + pix] = f2bf(v.w);
            }
        }
    }
    __syncthreads();   // barrier #1: image staged + h2 ready

    // ==== head: w = h2 @ W3 + b3, all 4 samples, stored bf16 ====
    // (reference materializes w as bf16 too — rounding here tracks the ref)
    {
        float h2r[4][16];
        const float4* hp = (const float4*)&s_h2[0][0];
#pragma unroll
        for (int i = 0; i < 16; ++i) {
            float4 v = hp[i];
            h2r[i >> 2][(i & 3) * 4 + 0] = v.x;
            h2r[i >> 2][(i & 3) * 4 + 1] = v.y;
            h2r[i >> 2][(i & 3) * 4 + 2] = v.z;
            h2r[i >> 2][(i & 3) * 4 + 3] = v.w;
        }
        for (int j = t; j < 811; j += BLK) {
            float bb = b3_bf ? bf2f(((const unsigned short*)b3)[j])
                             : ((const float*)b3)[j];
            float a0 = bb, a1 = bb, a2 = bb, a3 = bb;
            if (w3_bf) {
                const unsigned short* q = (const unsigned short*)W3 + j;
#pragma unroll
                for (int k = 0; k < 16; ++k) {
                    float w = bf2f(q[k * 811]);
                    a0 += h2r[0][k] * w; a1 += h2r[1][k] * w;
                    a2 += h2r[2][k] * w; a3 += h2r[3][k] * w;
                }
            } else {
                const float* q = (const float*)W3 + j;
#pragma unroll
                for (int k = 0; k < 16; ++k) {
                    float w = q[k * 811];
                    a0 += h2r[0][k] * w; a1 += h2r[1][k] * w;
                    a2 += h2r[2][k] * w; a3 += h2r[3][k] * w;
                }
            }
            su[0 * 2 * REG + HWW + j] = f2bf(a0);
            su[1 * 2 * REG + HWW + j] = f2bf(a1);
            su[2 * 2 * REG + HWW + j] = f2bf(a2);
            su[3 * 2 * REG + HWW + j] = f2bf(a3);
        }
    }
    __syncthreads();   // barrier #2: weights ready — conv phase is wave-local

    // ==== per-wave CNN: wave wv owns sample b0+wv ====
    const int sb  = wv * REG;        // dword base
    const int sb2 = wv * 2 * REG;    // halfword base

    // ---- conv1 (1->3, 28x28 -> fused pool -> 13x13x3 bf16) ----
    {
        float wc[27], cb[3];
#pragma unroll
        for (int i = 0; i < 27; ++i) wc[i] = bf2f(su[sb2 + HWW + i]);
#pragma unroll
        for (int c = 0; c < 3; ++c) cb[c] = bf2f(su[sb2 + HWW + 27 + c]);
        const unsigned* suw = (const unsigned*)&SH[sb];  // 2 pixels per dword
#pragma unroll
        for (int it = 0; it < 3; ++it) {
            int pix = lane + it * 64;
            if (pix < 169) {
                int py = pix / 13, px = pix - py * 13;
                int iy = 2 * py;
                float pt[4][4];
#pragma unroll
                for (int dy = 0; dy < 4; ++dy) {
                    int r = (iy + dy) * 14 + px;
                    unsigned d0 = suw[r], d1 = suw[r + 1];
                    pt[dy][0] = __uint_as_float(d0 << 16);
                    pt[dy][1] = __uint_as_float(d0 & 0xffff0000u);
                    pt[dy][2] = __uint_as_float(d1 << 16);
                    pt[dy][3] = __uint_as_float(d1 & 0xffff0000u);
                }
                unsigned short* op = &su[sb2 + HW_P1 + py * 14 + px];
#pragma unroll
                for (int c = 0; c < 3; ++c) {
                    float a00 = 0.f, a01 = 0.f, a10 = 0.f, a11 = 0.f;
#pragma unroll
                    for (int ky = 0; ky < 3; ++ky)
#pragma unroll
                        for (int kx = 0; kx < 3; ++kx) {
                            float w = wc[c * 9 + ky * 3 + kx];
                            a00 += pt[ky][kx] * w;
                            a01 += pt[ky][kx + 1] * w;
                            a10 += pt[ky + 1][kx] * w;
                            a11 += pt[ky + 1][kx + 1] * w;
                        }
                    float m = fmaxf(fmaxf(a00, a01), fmaxf(a10, a11));
                    op[c * 182] = f2bf(fmaxf(m + cb[c], 0.f));
                }
            }
        }
    }
    wsync();

    // ---- conv2 (3->6, 13x13 -> fused pool -> 5x5x6 fp32), ci-outer ----
    {
        int g = lane >> 5, q = lane & 31;
        if (q < 25) {
            int py = q / 5, px = q - py * 5;
            const unsigned* p1w = (const unsigned*)&SH[sb + DW_P1];
            float acc[3][4];
#pragma unroll
            for (int it = 0; it < 3; ++it)
#pragma unroll
                for (int i = 0; i < 4; ++i) acc[it][i] = 0.f;
#pragma unroll
            for (int ci = 0; ci < 3; ++ci) {
                float pt[4][4];
#pragma unroll
                for (int dy = 0; dy < 4; ++dy) {
                    int r = ci * 91 + (2 * py + dy) * 7 + px;
                    unsigned d0 = p1w[r], d1 = p1w[r + 1];
                    pt[dy][0] = __uint_as_float(d0 << 16);
                    pt[dy][1] = __uint_as_float(d0 & 0xffff0000u);
                    pt[dy][2] = __uint_as_float(d1 << 16);
                    pt[dy][3] = __uint_as_float(d1 & 0xffff0000u);
                }
#pragma unroll
                for (int it = 0; it < 3; ++it) {
                    int c = it * 2 + g;
                    const int wo = sb2 + HWW + 30 + c * 27 + ci;
#pragma unroll
                    for (int ky = 0; ky < 3; ++ky)
#pragma unroll
                        for (int kx = 0; kx < 3; ++kx) {
                            float w = bf2f(su[wo + (ky * 3 + kx) * 3]);
                            acc[it][0] += pt[ky][kx] * w;
                            acc[it][1] += pt[ky][kx + 1] * w;
                            acc[it][2] += pt[ky + 1][kx] * w;
                            acc[it][3] += pt[ky + 1][kx + 1] * w;
                        }
                }
            }
#pragma unroll
            for (int it = 0; it < 3; ++it) {
                int c = it * 2 + g;
                float m = fmaxf(fmaxf(acc[it][0], acc[it][1]),
                                fmaxf(acc[it][2], acc[it][3]));
                SH[sb + OFF_P2 + c * 25 + q] =
                    fmaxf(m + bf2f(su[sb2 + HWW + 192 + c]), 0.f);
            }
        }
    }
    wsync();

    // ---- conv3 (6->3, 5x5 -> 3x3) + relu, 54-lane split over ci halves ----
    {
        float acc = 0.f;
        int pq = lane % 27;            // 0..26: c*9 + pos
        int half = lane / 27;          // 0,1 active; lane>=54 idle
        int c = pq / 9, pos = pq - c * 9;
        int py = pos / 3, px = pos - py * 3;
        if (lane < 54) {
            const int wo = sb2 + HWW + 198 + c * 54;
            const int cb3 = half * 3;
#pragma unroll
            for (int ky = 0; ky < 3; ++ky)
#pragma unroll
                for (int kx = 0; kx < 3; ++kx)
#pragma unroll
                    for (int ci = 0; ci < 3; ++ci)
                        acc += SH[sb + OFF_P2 + (cb3 + ci) * 25 + (py + ky) * 5 + px + kx] *
                               bf2f(su[wo + (ky * 3 + kx) * 6 + cb3 + ci]);
        }
        float other = __shfl(acc, (lane + 27) & 63);
        if (lane < 27)
            SH[sb + OFF_P3 + pq] =
                fmaxf(acc + other + bf2f(su[sb2 + HWW + 360 + c]), 0.f);
    }
    wsync();

    // ---- conv4 (3->16) + bias + residual -> out, 32-lane split over pp ----
    // P3 channel-major (ci*9+pp), w4 spatial-major (pp*3+ci).
    {
        float acc = 0.f;
        int os = lane & 15, h = (lane >> 4) & 1;
        if (lane < 32) {
            const int wo = sb2 + HWW + 363 + os * 27;
            int p0 = h ? 4 : 0, p1 = h ? 9 : 4;
            for (int pp = p0; pp < p1; ++pp)
#pragma unroll
                for (int ci = 0; ci < 3; ++ci)
                    acc += SH[sb + OFF_P3 + ci * 9 + pp] *
                           bf2f(su[wo + pp * 3 + ci]);
        }
        float other = __shfl(acc, (lane + 16) & 63);
        if (lane < 16) {
            float tot = acc + other + bf2f(su[sb2 + HWW + 795 + os]) + s_st[wv][os];
            int gi = (b0 + wv) * 16 + os;
            if (out_bf) ((unsigned short*)out)[gi] = f2bf(tot);
            else        ((float*)out)[gi] = tot;
        }
    }
}

extern "C" void kernel_launch(void* const* d_in, const int* in_sizes, int n_in,
                              void* d_out, int out_size, void* d_ws, size_t ws_size,
                              hipStream_t stream) {
    (void)d_ws; (void)ws_size; (void)n_in; (void)out_size;
    int B = in_sizes[1] / 16;              // 16384
    int nblocks = B / NSAMP;               // 4096
    int nswz = (nblocks % 8 == 0) ? (nblocks / 8) : 0;

    dyncnn4_kernel<<<nblocks, BLK, 0, stream>>>(
        d_in[0], d_in[1], d_in[2], d_in[3], d_in[4], d_in[5], d_in[6], d_in[7],
        d_out, B, nswz);
}

// Round 10
// 162.276 us; speedup vs baseline: 1.2934x; 1.0064x over previous
//
#include <hip/hip_runtime.h>

#define BLK   512
#define NSAMP 8
#define REG   1072          // dwords per sample LDS region (4288 B)
// per-sample region map:
//  IMG:  halfwords [0..783] = dw [0..391] (bf16; dead after conv1)
//  P2:   dw [0..149]   (5x5x6 fp32, c*25+pos)   -- aliases dead IMG
//  P3:   dw [152..178] (3x3x3 fp32, c*9+pos)    -- aliases dead IMG
//  W:    halfwords [784..1594] (811 hypernet weights, bf16)
//  P1:   halfwords [1596..2141] (3ch * 13rows * stride14, bf16)
#define OFF_P2   0          // dw
#define OFF_P3   152        // dw
#define HWW      784        // halfword offset of W
#define HW_P1    1596       // halfword offset of P1
#define DW_P1    798        // dword offset of P1

// weight sub-offsets within W (SPLITS):
//  w1 0..27 (co*9+pp), b1 27..30, w2 30..192 (co*27+pp*3+ci), b2 192..198,
//  w3 198..360 (co*54+pp*6+ci), b3 360..363, w4 363..795 (co*27+pp*3+ci), b4 795..811

__device__ __forceinline__ float bf2f(unsigned short u) {
    return __uint_as_float(((unsigned int)u) << 16);
}
__device__ __forceinline__ unsigned short f2bf(float f) {
    unsigned int x = __float_as_uint(f);
    return (unsigned short)((x + 0x7fffu + ((x >> 16) & 1u)) >> 16);   // RNE
}
// wave-internal LDS ordering fence (DS retire + compiler barrier)
__device__ __forceinline__ void wsync() {
    __builtin_amdgcn_wave_barrier();
    __asm__ volatile("s_waitcnt lgkmcnt(0)" ::: "memory");
    __builtin_amdgcn_wave_barrier();
}

// Runtime dtype detection (proven R2..R9): probe EVEN halfwords.
// NOW RUN ONCE PER BLOCK (threads 0..7, one array each) — R9 ran it per-thread:
// ~128 probe loads + ~500 VALU per thread of pure overhead.
__device__ __forceinline__ bool is_bf16(const void* p, int elems) {
    const unsigned short* h = (const unsigned short*)p;
    int n = elems; if (n > 32) n = 32;
    int nz = 0, ok = 0;
    for (int i = 0; i < n; i += 2) {
        unsigned short u = h[i];
        if (u == 0) continue;
        ++nz;
        unsigned int e = (u >> 7) & 255u;
        if (e >= 100u && e <= 141u) ++ok;
    }
    if (nz < 4) return true;
    return 4 * ok >= 3 * nz;
}

// bound (512,4): VGPR cap 128 — no spill risk (R6/R8: spill sentinel is
// WRITE_SIZE ballooning). LDS ~35.9KB -> 4 blocks/CU = 32 waves static.
__global__ __launch_bounds__(BLK, 4)
void dyncnn4_kernel(const void* __restrict__ image,   // [784, B]
                    const void* __restrict__ state,   // [B, 16]
                    const void* __restrict__ W1, const void* __restrict__ b1,
                    const void* __restrict__ W2, const void* __restrict__ b2,
                    const void* __restrict__ W3, const void* __restrict__ b3,
                    void* __restrict__ out,           // [B,16]
                    int B, int nswz)
{
    __shared__ float SH[NSAMP * REG];     // 34304 B
    __shared__ float s_st[NSAMP][16];
    __shared__ float s_h1[NSAMP][16];
    __shared__ float s_h2[NSAMP][16];
    __shared__ unsigned char s_fl[8];

    const int t    = threadIdx.x;
    const int wv   = t >> 6;     // 0..7
    const int lane = t & 63;

    // ---- barrier #0: dtype flags, one array per thread 0..7 ----
    if (t < 8) {
        const void* q; int n;
        switch (t) {
            case 0:  q = image; n = 784 * B; break;
            case 1:  q = state; n = 16 * B;  break;
            case 2:  q = W1;    n = 256;     break;
            case 3:  q = b1;    n = 16;      break;
            case 4:  q = W2;    n = 256;     break;
            case 5:  q = b2;    n = 16;      break;
            case 6:  q = W3;    n = 12976;   break;
            default: q = b3;    n = 811;     break;
        }
        s_fl[t] = is_bf16(q, n) ? 1 : 0;
    }
    __syncthreads();
    const bool im_bf = s_fl[0], st_bf = s_fl[1], w1_bf = s_fl[2], b1_bf = s_fl[3];
    const bool w2_bf = s_fl[4], b2_bf = s_fl[5], w3_bf = s_fl[6], b3_bf = s_fl[7];
    const bool out_bf = im_bf && st_bf && w1_bf && w2_bf && w3_bf;

    int p = blockIdx.x;
    int l = (nswz > 0) ? ((p & 7) * nswz + (p >> 3)) : p;
    const int b0 = l * NSAMP;

    unsigned short* su = (unsigned short*)SH;   // halfword view

    // ==== phase 0: waves0-1 = MLP (4 samples each), waves2-7 = image staging ====
    if (wv < 2) {
        int s = wv * 4 + (lane >> 4), j = lane & 15;
        int gi = (b0 + s) * 16 + j;
        s_st[s][j] = st_bf ? bf2f(((const unsigned short*)state)[gi])
                           : ((const float*)state)[gi];
        wsync();
        float acc = b1_bf ? bf2f(((const unsigned short*)b1)[j])
                          : ((const float*)b1)[j];
#pragma unroll
        for (int k = 0; k < 16; ++k) {
            float w = w1_bf ? bf2f(((const unsigned short*)W1)[k * 16 + j])
                            : ((const float*)W1)[k * 16 + j];
            acc += s_st[s][k] * w;
        }
        s_h1[s][j] = fmaxf(acc, 0.f);
        wsync();
        acc = b2_bf ? bf2f(((const unsigned short*)b2)[j])
                    : ((const float*)b2)[j];
#pragma unroll
        for (int k = 0; k < 16; ++k) {
            float w = w2_bf ? bf2f(((const unsigned short*)W2)[k * 16 + j])
                            : ((const float*)W2)[k * 16 + j];
            acc += s_h1[s][k] * w;
        }
        s_h2[s][j] = fmaxf(acc, 0.f);
    } else {
        if (im_bf) {
            const unsigned short* im = (const unsigned short*)image;
            for (int pix = t - 128; pix < 784; pix += 384) {
                const uint4 v = *(const uint4*)(im + pix * B + b0);  // 8 samples
                su[0 * 2 * REG + pix] = (unsigned short)(v.x);
                su[1 * 2 * REG + pix] = (unsigned short)(v.x >> 16);
                su[2 * 2 * REG + pix] = (unsigned short)(v.y);
                su[3 * 2 * REG + pix] = (unsigned short)(v.y >> 16);
                su[4 * 2 * REG + pix] = (unsigned short)(v.z);
                su[5 * 2 * REG + pix] = (unsigned short)(v.z >> 16);
                su[6 * 2 * REG + pix] = (unsigned short)(v.w);
                su[7 * 2 * REG + pix] = (unsigned short)(v.w >> 16);
            }
        } else {
            const float* im = (const float*)image;
            for (int pix = t - 128; pix < 784; pix += 384) {
                const float4 a = *(const float4*)(im + pix * B + b0);
                const float4 c = *(const float4*)(im + pix * B + b0 + 4);
                su[0 * 2 * REG + pix] = f2bf(a.x);
                su[1 * 2 * REG + pix] = f2bf(a.y);
                su[2 * 2 * REG + pix] = f2bf(a.z);
                su[3 * 2 * REG + pix] = f2bf(a.w);
                su[4 * 2 * REG + pix] = f2bf(c.x);
                su[5 * 2 * REG + pix] = f2bf(c.y);
                su[6 * 2 * REG + pix] = f2bf(c.z);
                su[7 * 2 * REG + pix] = f2bf(c.w);
            }
        }
    }
    __syncthreads();   // barrier #1: image staged + h2 ready

    // ==== head: w = h2 @ W3 + b3; 4 passes of 2 samples; one W3 walk covers 8 ====
#pragma unroll
    for (int sp = 0; sp < NSAMP; sp += 2) {
        float h2a[16], h2b[16];
#pragma unroll
        for (int k = 0; k < 16; ++k) { h2a[k] = s_h2[sp][k]; h2b[k] = s_h2[sp + 1][k]; }
        for (int j = t; j < 811; j += BLK) {
            float bb = b3_bf ? bf2f(((const unsigned short*)b3)[j])
                             : ((const float*)b3)[j];
            float aa = bb, ab = bb;
            if (w3_bf) {
                const unsigned short* q = (const unsigned short*)W3 + j;
#pragma unroll
                for (int k = 0; k < 16; ++k) {
                    float w = bf2f(q[k * 811]);
                    aa += h2a[k] * w; ab += h2b[k] * w;
                }
            } else {
                const float* q = (const float*)W3 + j;
#pragma unroll
                for (int k = 0; k < 16; ++k) {
                    float w = q[k * 811];
                    aa += h2a[k] * w; ab += h2b[k] * w;
                }
            }
            su[sp * 2 * REG + HWW + j]       = f2bf(aa);
            su[(sp + 1) * 2 * REG + HWW + j] = f2bf(ab);
        }
    }
    __syncthreads();   // barrier #2: weights ready — conv phase is wave-local

    // ==== per-wave CNN: wave wv owns sample b0+wv ====
    const int sb  = wv * REG;        // dword base
    const int sb2 = wv * 2 * REG;    // halfword base

    // ---- conv1 (1->3, 28x28 -> fused pool -> 13x13x3 bf16) ----
    {
        float wc[27], cb[3];
#pragma unroll
        for (int i = 0; i < 27; ++i) wc[i] = bf2f(su[sb2 + HWW + i]);
#pragma unroll
        for (int c = 0; c < 3; ++c) cb[c] = bf2f(su[sb2 + HWW + 27 + c]);
        const unsigned* suw = (const unsigned*)&SH[sb];  // 2 pixels per dword
#pragma unroll
        for (int it = 0; it < 3; ++it) {
            int pix = lane + it * 64;
            if (pix < 169) {
                int py = pix / 13, px = pix - py * 13;
                int iy = 2 * py;
                float pt[4][4];
#pragma unroll
                for (int dy = 0; dy < 4; ++dy) {
                    int r = (iy + dy) * 14 + px;
                    unsigned d0 = suw[r], d1 = suw[r + 1];
                    pt[dy][0] = __uint_as_float(d0 << 16);
                    pt[dy][1] = __uint_as_float(d0 & 0xffff0000u);
                    pt[dy][2] = __uint_as_float(d1 << 16);
                    pt[dy][3] = __uint_as_float(d1 & 0xffff0000u);
                }
                unsigned short* op = &su[sb2 + HW_P1 + py * 14 + px];
#pragma unroll
                for (int c = 0; c < 3; ++c) {
                    float a00 = 0.f, a01 = 0.f, a10 = 0.f, a11 = 0.f;
#pragma unroll
                    for (int ky = 0; ky < 3; ++ky)
#pragma unroll
                        for (int kx = 0; kx < 3; ++kx) {
                            float w = wc[c * 9 + ky * 3 + kx];
                            a00 += pt[ky][kx] * w;
                            a01 += pt[ky][kx + 1] * w;
                            a10 += pt[ky + 1][kx] * w;
                            a11 += pt[ky + 1][kx + 1] * w;
                        }
                    float m = fmaxf(fmaxf(a00, a01), fmaxf(a10, a11));
                    op[c * 182] = f2bf(fmaxf(m + cb[c], 0.f));
                }
            }
        }
    }
    wsync();

    // ---- conv2 (3->6, 13x13 -> fused pool -> 5x5x6 fp32), ci-outer ----
    {
        int g = lane >> 5, q = lane & 31;
        if (q < 25) {
            int py = q / 5, px = q - py * 5;
            const unsigned* p1w = (const unsigned*)&SH[sb + DW_P1];
            float acc[3][4];
#pragma unroll
            for (int it = 0; it < 3; ++it)
#pragma unroll
                for (int i = 0; i < 4; ++i) acc[it][i] = 0.f;
#pragma unroll
            for (int ci = 0; ci < 3; ++ci) {
                float pt[4][4];
#pragma unroll
                for (int dy = 0; dy < 4; ++dy) {
                    int r = ci * 91 + (2 * py + dy) * 7 + px;
                    unsigned d0 = p1w[r], d1 = p1w[r + 1];
                    pt[dy][0] = __uint_as_float(d0 << 16);
                    pt[dy][1] = __uint_as_float(d0 & 0xffff0000u);
                    pt[dy][2] = __uint_as_float(d1 << 16);
                    pt[dy][3] = __uint_as_float(d1 & 0xffff0000u);
                }
#pragma unroll
                for (int it = 0; it < 3; ++it) {
                    int c = it * 2 + g;
                    const int wo = sb2 + HWW + 30 + c * 27 + ci;
#pragma unroll
                    for (int ky = 0; ky < 3; ++ky)
#pragma unroll
                        for (int kx = 0; kx < 3; ++kx) {
                            float w = bf2f(su[wo + (ky * 3 + kx) * 3]);
                            acc[it][0] += pt[ky][kx] * w;
                            acc[it][1] += pt[ky][kx + 1] * w;
                            acc[it][2] += pt[ky + 1][kx] * w;
                            acc[it][3] += pt[ky + 1][kx + 1] * w;
                        }
                }
            }
#pragma unroll
            for (int it = 0; it < 3; ++it) {
                int c = it * 2 + g;
                float m = fmaxf(fmaxf(acc[it][0], acc[it][1]),
                                fmaxf(acc[it][2], acc[it][3]));
                SH[sb + OFF_P2 + c * 25 + q] =
                    fmaxf(m + bf2f(su[sb2 + HWW + 192 + c]), 0.f);
            }
        }
    }
    wsync();

    // ---- conv3 (6->3, 5x5 -> 3x3) + relu, 54-lane split over ci halves ----
    {
        float acc = 0.f;
        int pq = lane % 27;            // 0..26: c*9 + pos
        int half = lane / 27;          // 0,1 active; lane>=54 idle
        int c = pq / 9, pos = pq - c * 9;
        int py = pos / 3, px = pos - py * 3;
        if (lane < 54) {
            const int wo = sb2 + HWW + 198 + c * 54;
            const int cb3 = half * 3;
#pragma unroll
            for (int ky = 0; ky < 3; ++ky)
#pragma unroll
                for (int kx = 0; kx < 3; ++kx)
#pragma unroll
                    for (int ci = 0; ci < 3; ++ci)
                        acc += SH[sb + OFF_P2 + (cb3 + ci) * 25 + (py + ky) * 5 + px + kx] *
                               bf2f(su[wo + (ky * 3 + kx) * 6 + cb3 + ci]);
        }
        float other = __shfl(acc, (lane + 27) & 63);
        if (lane < 27)
            SH[sb + OFF_P3 + pq] =
                fmaxf(acc + other + bf2f(su[sb2 + HWW + 360 + c]), 0.f);
    }
    wsync();

    // ---- conv4 (3->16) + bias + residual -> out, 32-lane split over pp ----
    // P3 channel-major (ci*9+pp), w4 spatial-major (pp*3+ci).
    {
        float acc = 0.f;
        int os = lane & 15, h = (lane >> 4) & 1;
        if (lane < 32) {
            const int wo = sb2 + HWW + 363 + os * 27;
            int p0 = h ? 4 : 0, p1 = h ? 9 : 4;
            for (int pp = p0; pp < p1; ++pp)
#pragma unroll
                for (int ci = 0; ci < 3; ++ci)
                    acc += SH[sb + OFF_P3 + ci * 9 + pp] *
                           bf2f(su[wo + pp * 3 + ci]);
        }
        float other = __shfl(acc, (lane + 16) & 63);
        if (lane < 16) {
            float tot = acc + other + bf2f(su[sb2 + HWW + 795 + os]) + s_st[wv][os];
            int gi = (b0 + wv) * 16 + os;
            if (out_bf) ((unsigned short*)out)[gi] = f2bf(tot);
            else        ((float*)out)[gi] = tot;
        }
    }
}

extern "C" void kernel_launch(void* const* d_in, const int* in_sizes, int n_in,
                              void* d_out, int out_size, void* d_ws, size_t ws_size,
                              hipStream_t stream) {
    (void)d_ws; (void)ws_size; (void)n_in; (void)out_size;
    int B = in_sizes[1] / 16;              // 16384
    int nblocks = B / NSAMP;               // 2048
    int nswz = (nblocks % 8 == 0) ? (nblocks / 8) : 0;

    dyncnn4_kernel<<<nblocks, BLK, 0, stream>>>(
        d_in[0], d_in[1], d_in[2], d_in[3], d_in[4], d_in[5], d_in[6], d_in[7],
        d_out, B, nswz);
}

// Round 11
// 149.032 us; speedup vs baseline: 1.4083x; 1.0889x over previous
//
#include <hip/hip_runtime.h>

#define BLK   512
#define NSAMP 8
#define REG   1480          // dwords per sample LDS region (5920 B)
// per-sample region map:
//  IMG:  halfwords [0..783] = dw [0..391] (bf16; dead after conv1)
//  P2:   dw [0..149]   (5x5x6 fp32, c*25+pos)   -- aliases dead IMG
//  P3:   dw [152..178] (3x3x3 fp32, c*9+pos)    -- aliases dead IMG
//  W:    dw [392..1203] (811 hypernet weights, fp32)
//  P1:   halfwords [2408..2953] = dw [1204..1476] (3ch * 13rows * stride14, bf16)
#define OFF_P2   0          // dw
#define OFF_P3   152        // dw
#define OFF_W    392        // dw (fp32 weights: R7-vs-R9 A/B showed fp32 W ~7% faster)
#define HW_P1    2408       // halfword offset of P1
#define DW_P1    1204       // dword offset of P1

// weight sub-offsets within W (SPLITS):
//  w1 0..27 (co*9+pp), b1 27..30, w2 30..192 (co*27+pp*3+ci), b2 192..198,
//  w3 198..360 (co*54+pp*6+ci), b3 360..363, w4 363..795 (co*27+pp*3+ci), b4 795..811

__device__ __forceinline__ float bf2f(unsigned short u) {
    return __uint_as_float(((unsigned int)u) << 16);
}
__device__ __forceinline__ unsigned short f2bf(float f) {
    unsigned int x = __float_as_uint(f);
    return (unsigned short)((x + 0x7fffu + ((x >> 16) & 1u)) >> 16);   // RNE
}
// wave-internal LDS ordering fence (DS retire + compiler barrier)
__device__ __forceinline__ void wsync() {
    __builtin_amdgcn_wave_barrier();
    __asm__ volatile("s_waitcnt lgkmcnt(0)" ::: "memory");
    __builtin_amdgcn_wave_barrier();
}

// Runtime dtype detection (proven R2..R10): probe EVEN halfwords.
// Run once per block (threads 0..7, one array each).
__device__ __forceinline__ bool is_bf16(const void* p, int elems) {
    const unsigned short* h = (const unsigned short*)p;
    int n = elems; if (n > 32) n = 32;
    int nz = 0, ok = 0;
    for (int i = 0; i < n; i += 2) {
        unsigned short u = h[i];
        if (u == 0) continue;
        ++nz;
        unsigned int e = (u >> 7) & 255u;
        if (e >= 100u && e <= 141u) ++ok;
    }
    if (nz < 4) return true;
    return 4 * ok >= 3 * nz;
}

// bound (512,4): VGPR cap 128 — no spill risk (R6/R8 lesson: spill sentinel is
// WRITE_SIZE ballooning). NO ext_vector arrays (R8: scratch-lowering trap).
__global__ __launch_bounds__(BLK, 4)
void dyncnn4_kernel(const void* __restrict__ image,   // [784, B]
                    const void* __restrict__ state,   // [B, 16]
                    const void* __restrict__ W1, const void* __restrict__ b1,
                    const void* __restrict__ W2, const void* __restrict__ b2,
                    const void* __restrict__ W3, const void* __restrict__ b3,
                    void* __restrict__ out,           // [B,16]
                    int B, int nswz)
{
    __shared__ float SH[NSAMP * REG];     // 47360 B
    __shared__ float s_st[NSAMP][16];
    __shared__ float s_h1[NSAMP][16];
    __shared__ float s_h2[NSAMP][16];
    __shared__ unsigned char s_fl[8];

    const int t    = threadIdx.x;
    const int wv   = t >> 6;     // 0..7
    const int lane = t & 63;

    // ---- barrier #0: dtype flags, one array per thread 0..7 ----
    if (t < 8) {
        const void* q; int n;
        switch (t) {
            case 0:  q = image; n = 784 * B; break;
            case 1:  q = state; n = 16 * B;  break;
            case 2:  q = W1;    n = 256;     break;
            case 3:  q = b1;    n = 16;      break;
            case 4:  q = W2;    n = 256;     break;
            case 5:  q = b2;    n = 16;      break;
            case 6:  q = W3;    n = 12976;   break;
            default: q = b3;    n = 811;     break;
        }
        s_fl[t] = is_bf16(q, n) ? 1 : 0;
    }
    __syncthreads();
    const bool im_bf = s_fl[0], st_bf = s_fl[1], w1_bf = s_fl[2], b1_bf = s_fl[3];
    const bool w2_bf = s_fl[4], b2_bf = s_fl[5], w3_bf = s_fl[6], b3_bf = s_fl[7];
    const bool out_bf = im_bf && st_bf && w1_bf && w2_bf && w3_bf;

    int p = blockIdx.x;
    int l = (nswz > 0) ? ((p & 7) * nswz + (p >> 3)) : p;
    const int b0 = l * NSAMP;

    unsigned short* su = (unsigned short*)SH;   // halfword view

    // ==== phase 0: waves0-1 = MLP (4 samples each), waves2-7 = image staging ====
    if (wv < 2) {
        int s = wv * 4 + (lane >> 4), j = lane & 15;
        int gi = (b0 + s) * 16 + j;
        s_st[s][j] = st_bf ? bf2f(((const unsigned short*)state)[gi])
                           : ((const float*)state)[gi];
        wsync();
        float acc = b1_bf ? bf2f(((const unsigned short*)b1)[j])
                          : ((const float*)b1)[j];
#pragma unroll
        for (int k = 0; k < 16; ++k) {
            float w = w1_bf ? bf2f(((const unsigned short*)W1)[k * 16 + j])
                            : ((const float*)W1)[k * 16 + j];
            acc += s_st[s][k] * w;
        }
        s_h1[s][j] = fmaxf(acc, 0.f);
        wsync();
        acc = b2_bf ? bf2f(((const unsigned short*)b2)[j])
                    : ((const float*)b2)[j];
#pragma unroll
        for (int k = 0; k < 16; ++k) {
            float w = w2_bf ? bf2f(((const unsigned short*)W2)[k * 16 + j])
                            : ((const float*)W2)[k * 16 + j];
            acc += s_h1[s][k] * w;
        }
        s_h2[s][j] = fmaxf(acc, 0.f);
    } else {
        if (im_bf) {
            const unsigned short* im = (const unsigned short*)image;
            for (int pix = t - 128; pix < 784; pix += 384) {
                const uint4 v = *(const uint4*)(im + pix * B + b0);  // 8 samples
                su[0 * 2 * REG + pix] = (unsigned short)(v.x);
                su[1 * 2 * REG + pix] = (unsigned short)(v.x >> 16);
                su[2 * 2 * REG + pix] = (unsigned short)(v.y);
                su[3 * 2 * REG + pix] = (unsigned short)(v.y >> 16);
                su[4 * 2 * REG + pix] = (unsigned short)(v.z);
                su[5 * 2 * REG + pix] = (unsigned short)(v.z >> 16);
                su[6 * 2 * REG + pix] = (unsigned short)(v.w);
                su[7 * 2 * REG + pix] = (unsigned short)(v.w >> 16);
            }
        } else {
            const float* im = (const float*)image;
            for (int pix = t - 128; pix < 784; pix += 384) {
                const float4 a = *(const float4*)(im + pix * B + b0);
                const float4 c = *(const float4*)(im + pix * B + b0 + 4);
                su[0 * 2 * REG + pix] = f2bf(a.x);
                su[1 * 2 * REG + pix] = f2bf(a.y);
                su[2 * 2 * REG + pix] = f2bf(a.z);
                su[3 * 2 * REG + pix] = f2bf(a.w);
                su[4 * 2 * REG + pix] = f2bf(c.x);
                su[5 * 2 * REG + pix] = f2bf(c.y);
                su[6 * 2 * REG + pix] = f2bf(c.z);
                su[7 * 2 * REG + pix] = f2bf(c.w);
            }
        }
    }
    __syncthreads();   // barrier #1: image staged + h2 ready

    // ==== head: w = h2 @ W3 + b3; 4 passes of 2 samples; stored fp32 ====
#pragma unroll
    for (int sp = 0; sp < NSAMP; sp += 2) {
        float h2a[16], h2b[16];
#pragma unroll
        for (int k = 0; k < 16; ++k) { h2a[k] = s_h2[sp][k]; h2b[k] = s_h2[sp + 1][k]; }
        for (int j = t; j < 811; j += BLK) {
            float bb = b3_bf ? bf2f(((const unsigned short*)b3)[j])
                             : ((const float*)b3)[j];
            float aa = bb, ab = bb;
            if (w3_bf) {
                const unsigned short* q = (const unsigned short*)W3 + j;
#pragma unroll
                for (int k = 0; k < 16; ++k) {
                    float w = bf2f(q[k * 811]);
                    aa += h2a[k] * w; ab += h2b[k] * w;
                }
            } else {
                const float* q = (const float*)W3 + j;
#pragma unroll
                for (int k = 0; k < 16; ++k) {
                    float w = q[k * 811];
                    aa += h2a[k] * w; ab += h2b[k] * w;
                }
            }
            SH[sp * REG + OFF_W + j]       = aa;
            SH[(sp + 1) * REG + OFF_W + j] = ab;
        }
    }
    __syncthreads();   // barrier #2: weights ready — conv phase is wave-local

    // ==== per-wave CNN: wave wv owns sample b0+wv ====
    const int sb  = wv * REG;        // dword base
    const int sb2 = wv * 2 * REG;    // halfword base

    // ---- conv1 (1->3, 28x28 -> fused pool -> 13x13x3 bf16) ----
    {
        float wc[27], cb[3];
#pragma unroll
        for (int i = 0; i < 27; ++i) wc[i] = SH[sb + OFF_W + i];
#pragma unroll
        for (int c = 0; c < 3; ++c) cb[c] = SH[sb + OFF_W + 27 + c];
        const unsigned* suw = (const unsigned*)&SH[sb];  // 2 pixels per dword
#pragma unroll
        for (int it = 0; it < 3; ++it) {
            int pix = lane + it * 64;
            if (pix < 169) {
                int py = pix / 13, px = pix - py * 13;
                int iy = 2 * py;
                float pt[4][4];
#pragma unroll
                for (int dy = 0; dy < 4; ++dy) {
                    int r = (iy + dy) * 14 + px;
                    unsigned d0 = suw[r], d1 = suw[r + 1];
                    pt[dy][0] = __uint_as_float(d0 << 16);
                    pt[dy][1] = __uint_as_float(d0 & 0xffff0000u);
                    pt[dy][2] = __uint_as_float(d1 << 16);
                    pt[dy][3] = __uint_as_float(d1 & 0xffff0000u);
                }
                unsigned short* op = &su[sb2 + HW_P1 + py * 14 + px];
#pragma unroll
                for (int c = 0; c < 3; ++c) {
                    float a00 = 0.f, a01 = 0.f, a10 = 0.f, a11 = 0.f;
#pragma unroll
                    for (int ky = 0; ky < 3; ++ky)
#pragma unroll
                        for (int kx = 0; kx < 3; ++kx) {
                            float w = wc[c * 9 + ky * 3 + kx];
                            a00 += pt[ky][kx] * w;
                            a01 += pt[ky][kx + 1] * w;
                            a10 += pt[ky + 1][kx] * w;
                            a11 += pt[ky + 1][kx + 1] * w;
                        }
                    float m = fmaxf(fmaxf(a00, a01), fmaxf(a10, a11));
                    op[c * 182] = f2bf(fmaxf(m + cb[c], 0.f));
                }
            }
        }
    }
    wsync();

    // ---- conv2 (3->6, 13x13 -> fused pool -> 5x5x6 fp32), ci-outer ----
    {
        int g = lane >> 5, q = lane & 31;
        if (q < 25) {
            int py = q / 5, px = q - py * 5;
            const unsigned* p1w = (const unsigned*)&SH[sb + DW_P1];
            float acc[3][4];
#pragma unroll
            for (int it = 0; it < 3; ++it)
#pragma unroll
                for (int i = 0; i < 4; ++i) acc[it][i] = 0.f;
#pragma unroll
            for (int ci = 0; ci < 3; ++ci) {
                float pt[4][4];
#pragma unroll
                for (int dy = 0; dy < 4; ++dy) {
                    int r = ci * 91 + (2 * py + dy) * 7 + px;
                    unsigned d0 = p1w[r], d1 = p1w[r + 1];
                    pt[dy][0] = __uint_as_float(d0 << 16);
                    pt[dy][1] = __uint_as_float(d0 & 0xffff0000u);
                    pt[dy][2] = __uint_as_float(d1 << 16);
                    pt[dy][3] = __uint_as_float(d1 & 0xffff0000u);
                }
#pragma unroll
                for (int it = 0; it < 3; ++it) {
                    int c = it * 2 + g;
                    const int wo = sb + OFF_W + 30 + c * 27 + ci;
#pragma unroll
                    for (int ky = 0; ky < 3; ++ky)
#pragma unroll
                        for (int kx = 0; kx < 3; ++kx) {
                            float w = SH[wo + (ky * 3 + kx) * 3];
                            acc[it][0] += pt[ky][kx] * w;
                            acc[it][1] += pt[ky][kx + 1] * w;
                            acc[it][2] += pt[ky + 1][kx] * w;
                            acc[it][3] += pt[ky + 1][kx + 1] * w;
                        }
                }
            }
#pragma unroll
            for (int it = 0; it < 3; ++it) {
                int c = it * 2 + g;
                float m = fmaxf(fmaxf(acc[it][0], acc[it][1]),
                                fmaxf(acc[it][2], acc[it][3]));
                SH[sb + OFF_P2 + c * 25 + q] =
                    fmaxf(m + SH[sb + OFF_W + 192 + c], 0.f);
            }
        }
    }
    wsync();

    // ---- conv3 (6->3, 5x5 -> 3x3) + relu, 54-lane split over ci halves ----
    {
        float acc = 0.f;
        int pq = lane % 27;            // 0..26: c*9 + pos
        int half = lane / 27;          // 0,1 active; lane>=54 idle
        int c = pq / 9, pos = pq - c * 9;
        int py = pos / 3, px = pos - py * 3;
        if (lane < 54) {
            const int wo = sb + OFF_W + 198 + c * 54;
            const int cb3 = half * 3;
#pragma unroll
            for (int ky = 0; ky < 3; ++ky)
#pragma unroll
                for (int kx = 0; kx < 3; ++kx)
#pragma unroll
                    for (int ci = 0; ci < 3; ++ci)
                        acc += SH[sb + OFF_P2 + (cb3 + ci) * 25 + (py + ky) * 5 + px + kx] *
                               SH[wo + (ky * 3 + kx) * 6 + cb3 + ci];
        }
        float other = __shfl(acc, (lane + 27) & 63);
        if (lane < 27)
            SH[sb + OFF_P3 + pq] =
                fmaxf(acc + other + SH[sb + OFF_W + 360 + c], 0.f);
    }
    wsync();

    // ---- conv4 (3->16) + bias + residual -> out, 32-lane split over pp ----
    // P3 channel-major (ci*9+pp), w4 spatial-major (pp*3+ci).
    {
        float acc = 0.f;
        int os = lane & 15, h = (lane >> 4) & 1;
        if (lane < 32) {
            const int wo = sb + OFF_W + 363 + os * 27;
            int p0 = h ? 4 : 0, p1 = h ? 9 : 4;
            for (int pp = p0; pp < p1; ++pp)
#pragma unroll
                for (int ci = 0; ci < 3; ++ci)
                    acc += SH[sb + OFF_P3 + ci * 9 + pp] * SH[wo + pp * 3 + ci];
        }
        float other = __shfl(acc, (lane + 16) & 63);
        if (lane < 16) {
            float tot = acc + other + SH[sb + OFF_W + 795 + os] + s_st[wv][os];
            int gi = (b0 + wv) * 16 + os;
            if (out_bf) ((unsigned short*)out)[gi] = f2bf(tot);
            else        ((float*)out)[gi] = tot;
        }
    }
}

extern "C" void kernel_launch(void* const* d_in, const int* in_sizes, int n_in,
                              void* d_out, int out_size, void* d_ws, size_t ws_size,
                              hipStream_t stream) {
    (void)d_ws; (void)ws_size; (void)n_in; (void)out_size;
    int B = in_sizes[1] / 16;              // 16384
    int nblocks = B / NSAMP;               // 2048
    int nswz = (nblocks % 8 == 0) ? (nblocks / 8) : 0;

    dyncnn4_kernel<<<nblocks, BLK, 0, stream>>>(
        d_in[0], d_in[1], d_in[2], d_in[3], d_in[4], d_in[5], d_in[6], d_in[7],
        d_out, B, nswz);
}

// Round 12
// 142.686 us; speedup vs baseline: 1.4709x; 1.0445x over previous
//
#include <hip/hip_runtime.h>

#define BLK   512
#define NSAMP 8
#define REG   1480          // dwords per sample LDS region (5920 B)
// per-sample region map:
//  IMG:  halfwords [0..783] = dw [0..391] (bf16; dead after conv1)
//  P2:   dw [0..149]   (5x5x6 fp32, c*25+pos)   -- aliases dead IMG
//  P3:   dw [152..178] (3x3x3 fp32, c*9+pos)    -- aliases dead IMG
//  W:    dw [392..1203] (811 hypernet weights, fp32)
//  P1:   halfwords [2408..2953] = dw [1204..1476] (3ch * 13rows * stride14, bf16)
#define OFF_P2   0          // dw
#define OFF_P3   152        // dw
#define OFF_W    392        // dw (fp32 weights: R7-vs-R9 A/B showed fp32 W ~7% faster)
#define HW_P1    2408       // halfword offset of P1
#define DW_P1    1204       // dword offset of P1

// weight sub-offsets within W (SPLITS):
//  w1 0..27 (co*9+pp), b1 27..30, w2 30..192 (co*27+pp*3+ci), b2 192..198,
//  w3 198..360 (co*54+pp*6+ci), b3 360..363, w4 363..795 (co*27+pp*3+ci), b4 795..811

typedef short bf16x8 __attribute__((ext_vector_type(8)));   // 4 VGPRs (guide §3)
typedef float f32x4  __attribute__((ext_vector_type(4)));

__device__ __forceinline__ float bf2f(unsigned short u) {
    return __uint_as_float(((unsigned int)u) << 16);
}
__device__ __forceinline__ unsigned short f2bf(float f) {
    unsigned int x = __float_as_uint(f);
    return (unsigned short)((x + 0x7fffu + ((x >> 16) & 1u)) >> 16);   // RNE
}
// wave-internal LDS ordering fence (DS retire + compiler barrier)
__device__ __forceinline__ void wsync() {
    __builtin_amdgcn_wave_barrier();
    __asm__ volatile("s_waitcnt lgkmcnt(0)" ::: "memory");
    __builtin_amdgcn_wave_barrier();
}

// Runtime dtype detection (proven R2..R11): probe EVEN halfwords.
// Run once per block (threads 0..7, one array each).
__device__ __forceinline__ bool is_bf16(const void* p, int elems) {
    const unsigned short* h = (const unsigned short*)p;
    int n = elems; if (n > 32) n = 32;
    int nz = 0, ok = 0;
    for (int i = 0; i < n; i += 2) {
        unsigned short u = h[i];
        if (u == 0) continue;
        ++nz;
        unsigned int e = (u >> 7) & 255u;
        if (e >= 100u && e <= 141u) ++ok;
    }
    if (nz < 4) return true;
    return 4 * ok >= 3 * nz;
}

// bound (512,4): VGPR cap 128 — no spill risk (R6/R8 lesson: spill sentinel is
// WRITE_SIZE ballooning). NO ext_vector ARRAYS (R8 scratch trap) — single frag
// variables only.
__global__ __launch_bounds__(BLK, 4)
void dyncnn4_kernel(const void* __restrict__ image,   // [784, B]
                    const void* __restrict__ state,   // [B, 16]
                    const void* __restrict__ W1, const void* __restrict__ b1,
                    const void* __restrict__ W2, const void* __restrict__ b2,
                    const void* __restrict__ W3, const void* __restrict__ b3,
                    void* __restrict__ out,           // [B,16]
                    int B, int nswz)
{
    __shared__ float SH[NSAMP * REG];     // 47360 B
    __shared__ float s_st[NSAMP][16];
    __shared__ float s_h1[NSAMP][16];
    __shared__ float s_h2[NSAMP][16];
    __shared__ unsigned char s_fl[8];

    const int t    = threadIdx.x;
    const int wv   = t >> 6;     // 0..7
    const int lane = t & 63;

    // ---- barrier #0: dtype flags, one array per thread 0..7 ----
    if (t < 8) {
        const void* q; int n;
        switch (t) {
            case 0:  q = image; n = 784 * B; break;
            case 1:  q = state; n = 16 * B;  break;
            case 2:  q = W1;    n = 256;     break;
            case 3:  q = b1;    n = 16;      break;
            case 4:  q = W2;    n = 256;     break;
            case 5:  q = b2;    n = 16;      break;
            case 6:  q = W3;    n = 12976;   break;
            default: q = b3;    n = 811;     break;
        }
        s_fl[t] = is_bf16(q, n) ? 1 : 0;
    }
    __syncthreads();
    const bool im_bf = s_fl[0], st_bf = s_fl[1], w1_bf = s_fl[2], b1_bf = s_fl[3];
    const bool w2_bf = s_fl[4], b2_bf = s_fl[5], w3_bf = s_fl[6], b3_bf = s_fl[7];
    const bool out_bf = im_bf && st_bf && w1_bf && w2_bf && w3_bf;

    int p = blockIdx.x;
    int l = (nswz > 0) ? ((p & 7) * nswz + (p >> 3)) : p;
    const int b0 = l * NSAMP;

    unsigned short* su = (unsigned short*)SH;   // halfword view

    // ==== phase 0: waves0-1 = MLP (4 samples each), waves2-7 = image staging ====
    if (wv < 2) {
        int s = wv * 4 + (lane >> 4), j = lane & 15;
        int gi = (b0 + s) * 16 + j;
        s_st[s][j] = st_bf ? bf2f(((const unsigned short*)state)[gi])
                           : ((const float*)state)[gi];
        wsync();
        float acc = b1_bf ? bf2f(((const unsigned short*)b1)[j])
                          : ((const float*)b1)[j];
#pragma unroll
        for (int k = 0; k < 16; ++k) {
            float w = w1_bf ? bf2f(((const unsigned short*)W1)[k * 16 + j])
                            : ((const float*)W1)[k * 16 + j];
            acc += s_st[s][k] * w;
        }
        s_h1[s][j] = fmaxf(acc, 0.f);
        wsync();
        acc = b2_bf ? bf2f(((const unsigned short*)b2)[j])
                    : ((const float*)b2)[j];
#pragma unroll
        for (int k = 0; k < 16; ++k) {
            float w = w2_bf ? bf2f(((const unsigned short*)W2)[k * 16 + j])
                            : ((const float*)W2)[k * 16 + j];
            acc += s_h1[s][k] * w;
        }
        s_h2[s][j] = fmaxf(acc, 0.f);
    } else {
        // staging: prefetch both main loads before unpacking (hide HBM latency)
        int pix0 = t - 128;            // 0..383
        int pix1 = pix0 + 384;         // 384..767
        int pix2 = pix0 + 768;         // 768..1151 (valid only if < 784)
        if (im_bf) {
            const unsigned short* im = (const unsigned short*)image;
            const uint4 v0 = *(const uint4*)(im + pix0 * B + b0);
            const uint4 v1 = *(const uint4*)(im + pix1 * B + b0);
#pragma unroll
            for (int h = 0; h < 2; ++h) {
                const uint4 v = h ? v1 : v0;
                int pix = h ? pix1 : pix0;
                su[0 * 2 * REG + pix] = (unsigned short)(v.x);
                su[1 * 2 * REG + pix] = (unsigned short)(v.x >> 16);
                su[2 * 2 * REG + pix] = (unsigned short)(v.y);
                su[3 * 2 * REG + pix] = (unsigned short)(v.y >> 16);
                su[4 * 2 * REG + pix] = (unsigned short)(v.z);
                su[5 * 2 * REG + pix] = (unsigned short)(v.z >> 16);
                su[6 * 2 * REG + pix] = (unsigned short)(v.w);
                su[7 * 2 * REG + pix] = (unsigned short)(v.w >> 16);
            }
            if (pix2 < 784) {
                const uint4 v = *(const uint4*)(im + pix2 * B + b0);
                su[0 * 2 * REG + pix2] = (unsigned short)(v.x);
                su[1 * 2 * REG + pix2] = (unsigned short)(v.x >> 16);
                su[2 * 2 * REG + pix2] = (unsigned short)(v.y);
                su[3 * 2 * REG + pix2] = (unsigned short)(v.y >> 16);
                su[4 * 2 * REG + pix2] = (unsigned short)(v.z);
                su[5 * 2 * REG + pix2] = (unsigned short)(v.z >> 16);
                su[6 * 2 * REG + pix2] = (unsigned short)(v.w);
                su[7 * 2 * REG + pix2] = (unsigned short)(v.w >> 16);
            }
        } else {
            const float* im = (const float*)image;
            for (int pix = pix0; pix < 784; pix += 384) {
                const float4 a = *(const float4*)(im + pix * B + b0);
                const float4 c = *(const float4*)(im + pix * B + b0 + 4);
                su[0 * 2 * REG + pix] = f2bf(a.x);
                su[1 * 2 * REG + pix] = f2bf(a.y);
                su[2 * 2 * REG + pix] = f2bf(a.z);
                su[3 * 2 * REG + pix] = f2bf(a.w);
                su[4 * 2 * REG + pix] = f2bf(c.x);
                su[5 * 2 * REG + pix] = f2bf(c.y);
                su[6 * 2 * REG + pix] = f2bf(c.z);
                su[7 * 2 * REG + pix] = f2bf(c.w);
            }
        }
    }
    __syncthreads();   // barrier #1: image staged + h2 ready

    // ==== head via MFMA: w[8][811] = h2[8][16] @ W3[16][811] + b3 ====
    // v_mfma_f32_16x16x32_bf16, zero-padded to 16 rows / K=32.
    // A layout (m120): A[m=lane&15][k=(lane>>4)*8+i]; rows m>=8 and k>=16 zero.
    // B layout (symmetric): B[k=(lane>>4)*8+i][n=lane&15].
    // C/D layout (m89): col=lane&15, row=(lane>>4)*4+reg.
    {
        const int n  = lane & 15;
        const int kg = lane >> 4;        // 0..3; kg>=2 -> k>=16 -> zero pad
        bf16x8 afrag;
#pragma unroll
        for (int i = 0; i < 8; ++i) afrag[i] = 0;
        if (kg < 2 && n < 8) {
            const int k0 = kg * 8;
#pragma unroll
            for (int i = 0; i < 8; ++i)
                afrag[i] = (short)f2bf(s_h2[n][k0 + i]);
        }
        for (int tile = wv; tile < 51; tile += 8) {
            const int jn = tile * 16 + n;
            bf16x8 bfrag;
#pragma unroll
            for (int i = 0; i < 8; ++i) bfrag[i] = 0;
            if (kg < 2 && jn < 811) {
                const int k0 = kg * 8;
                if (w3_bf) {
                    const unsigned short* q = (const unsigned short*)W3 + k0 * 811 + jn;
#pragma unroll
                    for (int i = 0; i < 8; ++i) bfrag[i] = (short)q[i * 811];
                } else {
                    const float* q = (const float*)W3 + k0 * 811 + jn;
#pragma unroll
                    for (int i = 0; i < 8; ++i) bfrag[i] = (short)f2bf(q[i * 811]);
                }
            }
            f32x4 c = {0.f, 0.f, 0.f, 0.f};
            c = __builtin_amdgcn_mfma_f32_16x16x32_bf16(afrag, bfrag, c, 0, 0, 0);
            const int row0 = kg * 4;     // rows row0..row0+3
            if (row0 < 8 && jn < 811) {
                float bb = b3_bf ? bf2f(((const unsigned short*)b3)[jn])
                                 : ((const float*)b3)[jn];
#pragma unroll
                for (int r = 0; r < 4; ++r)
                    SH[(row0 + r) * REG + OFF_W + jn] = c[r] + bb;
            }
        }
    }
    __syncthreads();   // barrier #2: weights ready — conv phase is wave-local

    // ==== per-wave CNN: wave wv owns sample b0+wv ====
    const int sb  = wv * REG;        // dword base
    const int sb2 = wv * 2 * REG;    // halfword base

    // ---- conv1 (1->3, 28x28 -> fused pool -> 13x13x3 bf16) ----
    {
        float wc[27], cb[3];
#pragma unroll
        for (int i = 0; i < 27; ++i) wc[i] = SH[sb + OFF_W + i];
#pragma unroll
        for (int c = 0; c < 3; ++c) cb[c] = SH[sb + OFF_W + 27 + c];
        const unsigned* suw = (const unsigned*)&SH[sb];  // 2 pixels per dword
#pragma unroll
        for (int it = 0; it < 3; ++it) {
            int pix = lane + it * 64;
            if (pix < 169) {
                int py = pix / 13, px = pix - py * 13;
                int iy = 2 * py;
                float pt[4][4];
#pragma unroll
                for (int dy = 0; dy < 4; ++dy) {
                    int r = (iy + dy) * 14 + px;
                    unsigned d0 = suw[r], d1 = suw[r + 1];
                    pt[dy][0] = __uint_as_float(d0 << 16);
                    pt[dy][1] = __uint_as_float(d0 & 0xffff0000u);
                    pt[dy][2] = __uint_as_float(d1 << 16);
                    pt[dy][3] = __uint_as_float(d1 & 0xffff0000u);
                }
                unsigned short* op = &su[sb2 + HW_P1 + py * 14 + px];
#pragma unroll
                for (int c = 0; c < 3; ++c) {
                    float a00 = 0.f, a01 = 0.f, a10 = 0.f, a11 = 0.f;
#pragma unroll
                    for (int ky = 0; ky < 3; ++ky)
#pragma unroll
                        for (int kx = 0; kx < 3; ++kx) {
                            float w = wc[c * 9 + ky * 3 + kx];
                            a00 += pt[ky][kx] * w;
                            a01 += pt[ky][kx + 1] * w;
                            a10 += pt[ky + 1][kx] * w;
                            a11 += pt[ky + 1][kx + 1] * w;
                        }
                    float m = fmaxf(fmaxf(a00, a01), fmaxf(a10, a11));
                    op[c * 182] = f2bf(fmaxf(m + cb[c], 0.f));
                }
            }
        }
    }
    wsync();

    // ---- conv2 (3->6, 13x13 -> fused pool -> 5x5x6 fp32), ci-outer ----
    {
        int g = lane >> 5, q = lane & 31;
        if (q < 25) {
            int py = q / 5, px = q - py * 5;
            const unsigned* p1w = (const unsigned*)&SH[sb + DW_P1];
            float acc[3][4];
#pragma unroll
            for (int it = 0; it < 3; ++it)
#pragma unroll
                for (int i = 0; i < 4; ++i) acc[it][i] = 0.f;
#pragma unroll
            for (int ci = 0; ci < 3; ++ci) {
                float pt[4][4];
#pragma unroll
                for (int dy = 0; dy < 4; ++dy) {
                    int r = ci * 91 + (2 * py + dy) * 7 + px;
                    unsigned d0 = p1w[r], d1 = p1w[r + 1];
                    pt[dy][0] = __uint_as_float(d0 << 16);
                    pt[dy][1] = __uint_as_float(d0 & 0xffff0000u);
                    pt[dy][2] = __uint_as_float(d1 << 16);
                    pt[dy][3] = __uint_as_float(d1 & 0xffff0000u);
                }
#pragma unroll
                for (int it = 0; it < 3; ++it) {
                    int c = it * 2 + g;
                    const int wo = sb + OFF_W + 30 + c * 27 + ci;
#pragma unroll
                    for (int ky = 0; ky < 3; ++ky)
#pragma unroll
                        for (int kx = 0; kx < 3; ++kx) {
                            float w = SH[wo + (ky * 3 + kx) * 3];
                            acc[it][0] += pt[ky][kx] * w;
                            acc[it][1] += pt[ky][kx + 1] * w;
                            acc[it][2] += pt[ky + 1][kx] * w;
                            acc[it][3] += pt[ky + 1][kx + 1] * w;
                        }
                }
            }
#pragma unroll
            for (int it = 0; it < 3; ++it) {
                int c = it * 2 + g;
                float m = fmaxf(fmaxf(acc[it][0], acc[it][1]),
                                fmaxf(acc[it][2], acc[it][3]));
                SH[sb + OFF_P2 + c * 25 + q] =
                    fmaxf(m + SH[sb + OFF_W + 192 + c], 0.f);
            }
        }
    }
    wsync();

    // ---- conv3 (6->3, 5x5 -> 3x3) + relu, 54-lane split over ci halves ----
    {
        float acc = 0.f;
        int pq = lane % 27;            // 0..26: c*9 + pos
        int half = lane / 27;          // 0,1 active; lane>=54 idle
        int c = pq / 9, pos = pq - c * 9;
        int py = pos / 3, px = pos - py * 3;
        if (lane < 54) {
            const int wo = sb + OFF_W + 198 + c * 54;
            const int cb3 = half * 3;
#pragma unroll
            for (int ky = 0; ky < 3; ++ky)
#pragma unroll
                for (int kx = 0; kx < 3; ++kx)
#pragma unroll
                    for (int ci = 0; ci < 3; ++ci)
                        acc += SH[sb + OFF_P2 + (cb3 + ci) * 25 + (py + ky) * 5 + px + kx] *
                               SH[wo + (ky * 3 + kx) * 6 + cb3 + ci];
        }
        float other = __shfl(acc, (lane + 27) & 63);
        if (lane < 27)
            SH[sb + OFF_P3 + pq] =
                fmaxf(acc + other + SH[sb + OFF_W + 360 + c], 0.f);
    }
    wsync();

    // ---- conv4 (3->16) + bias + residual -> out, 32-lane split over pp ----
    // P3 channel-major (ci*9+pp), w4 spatial-major (pp*3+ci).
    {
        float acc = 0.f;
        int os = lane & 15, h = (lane >> 4) & 1;
        if (lane < 32) {
            const int wo = sb + OFF_W + 363 + os * 27;
            int p0 = h ? 4 : 0, p1 = h ? 9 : 4;
            for (int pp = p0; pp < p1; ++pp)
#pragma unroll
                for (int ci = 0; ci < 3; ++ci)
                    acc += SH[sb + OFF_P3 + ci * 9 + pp] * SH[wo + pp * 3 + ci];
        }
        float other = __shfl(acc, (lane + 16) & 63);
        if (lane < 16) {
            float tot = acc + other + SH[sb + OFF_W + 795 + os] + s_st[wv][os];
            int gi = (b0 + wv) * 16 + os;
            if (out_bf) ((unsigned short*)out)[gi] = f2bf(tot);
            else        ((float*)out)[gi] = tot;
        }
    }
}

extern "C" void kernel_launch(void* const* d_in, const int* in_sizes, int n_in,
                              void* d_out, int out_size, void* d_ws, size_t ws_size,
                              hipStream_t stream) {
    (void)d_ws; (void)ws_size; (void)n_in; (void)out_size;
    int B = in_sizes[1] / 16;              // 16384
    int nblocks = B / NSAMP;               // 2048
    int nswz = (nblocks % 8 == 0) ? (nblocks / 8) : 0;

    dyncnn4_kernel<<<nblocks, BLK, 0, stream>>>(
        d_in[0], d_in[1], d_in[2], d_in[3], d_in[4], d_in[5], d_in[6], d_in[7],
        d_out, B, nswz);
}

// Round 13
// 136.683 us; speedup vs baseline: 1.5355x; 1.0439x over previous
//
#include <hip/hip_runtime.h>

#define BLK   512
#define NSAMP 8
#define REG   1480          // dwords per sample LDS region (5920 B)
// per-sample region map:
//  IMG:  halfwords [0..783] = dw [0..391] (bf16; dead after conv1)
//  P2:   dw [0..149]   (5x5x6 fp32, c*25+pos)   -- aliases dead IMG
//  P3:   dw [152..178] (3x3x3 fp32, c*9+pos)    -- aliases dead IMG
//  W:    dw [392..1203] (811 hypernet weights, fp32, PERMUTED — see below)
//  P1:   halfwords [2408..2953] = dw [1204..1476] (3ch * 13rows * stride14, bf16)
#define OFF_P2   0          // dw
#define OFF_P3   152        // dw
#define OFF_W    392        // dw
#define HW_P1    2408       // halfword offset of P1
#define DW_P1    1204       // dword offset of P1

// W section layout (PERMUTED at head-write time so conv reads are contiguous):
//  w1 [0,27)   : [c][tap]      (unchanged — already contiguous for conv1 hoist)
//  b1 [27,30)
//  w2 [30,192) : [c][ci][tap]  (canonical is [c][tap][ci]; permuted for conv2)
//  b2 [192,198)
//  w3 [198,360): [c][ci][tap]  (canonical is [c][tap][ci]; permuted for conv3)
//  b3 [360,363)
//  w4 [363,795): [c][tap][ci]  (unchanged — conv4's pp,ci loop is already contiguous)
//  b4 [795,811)

typedef short bf16x8 __attribute__((ext_vector_type(8)));   // 4 VGPRs (guide §3)
typedef float f32x4  __attribute__((ext_vector_type(4)));

__device__ __forceinline__ float bf2f(unsigned short u) {
    return __uint_as_float(((unsigned int)u) << 16);
}
__device__ __forceinline__ unsigned short f2bf(float f) {
    unsigned int x = __float_as_uint(f);
    return (unsigned short)((x + 0x7fffu + ((x >> 16) & 1u)) >> 16);   // RNE
}
// wave-internal LDS ordering fence (DS retire + compiler barrier)
__device__ __forceinline__ void wsync() {
    __builtin_amdgcn_wave_barrier();
    __asm__ volatile("s_waitcnt lgkmcnt(0)" ::: "memory");
    __builtin_amdgcn_wave_barrier();
}

// Runtime dtype detection (proven R2..R12): probe EVEN halfwords.
__device__ __forceinline__ bool is_bf16(const void* p, int elems) {
    const unsigned short* h = (const unsigned short*)p;
    int n = elems; if (n > 32) n = 32;
    int nz = 0, ok = 0;
    for (int i = 0; i < n; i += 2) {
        unsigned short u = h[i];
        if (u == 0) continue;
        ++nz;
        unsigned int e = (u >> 7) & 255u;
        if (e >= 100u && e <= 141u) ++ok;
    }
    if (nz < 4) return true;
    return 4 * ok >= 3 * nz;
}

// head-write permutation: logical j -> stored index (see W section layout above)
__device__ __forceinline__ int wperm(int j) {
    if (j >= 30 && j < 192) {
        int rel = j - 30, c = rel / 27, r2 = rel - 27 * c;
        int tap = r2 / 3, ci = r2 - 3 * tap;
        return 30 + c * 27 + ci * 9 + tap;
    }
    if (j >= 198 && j < 360) {
        int rel = j - 198, c = rel / 54, r3 = rel - 54 * c;
        int tap = r3 / 6, ci = r3 - 6 * tap;
        return 198 + c * 54 + ci * 9 + tap;
    }
    return j;
}

// bound (512,4): VGPR cap 128 — no spill risk (R6/R8 lesson: spill sentinel is
// WRITE_SIZE ballooning). NO ext_vector ARRAYS (R8 scratch trap).
__global__ __launch_bounds__(BLK, 4)
void dyncnn4_kernel(const void* __restrict__ image,   // [784, B]
                    const void* __restrict__ state,   // [B, 16]
                    const void* __restrict__ W1, const void* __restrict__ b1,
                    const void* __restrict__ W2, const void* __restrict__ b2,
                    const void* __restrict__ W3, const void* __restrict__ b3,
                    void* __restrict__ out,           // [B,16]
                    int B, int nswz)
{
    __shared__ float SH[NSAMP * REG];     // 47360 B
    __shared__ float s_st[NSAMP][16];
    __shared__ float s_h1[NSAMP][16];
    __shared__ float s_h2[NSAMP][16];
    __shared__ unsigned char s_fl[8];

    const int t    = threadIdx.x;
    const int wv   = t >> 6;     // 0..7
    const int lane = t & 63;

    // ---- barrier #0: dtype flags, one array per thread 0..7 ----
    if (t < 8) {
        const void* q; int n;
        switch (t) {
            case 0:  q = image; n = 784 * B; break;
            case 1:  q = state; n = 16 * B;  break;
            case 2:  q = W1;    n = 256;     break;
            case 3:  q = b1;    n = 16;      break;
            case 4:  q = W2;    n = 256;     break;
            case 5:  q = b2;    n = 16;      break;
            case 6:  q = W3;    n = 12976;   break;
            default: q = b3;    n = 811;     break;
        }
        s_fl[t] = is_bf16(q, n) ? 1 : 0;
    }
    __syncthreads();
    const bool im_bf = s_fl[0], st_bf = s_fl[1], w1_bf = s_fl[2], b1_bf = s_fl[3];
    const bool w2_bf = s_fl[4], b2_bf = s_fl[5], w3_bf = s_fl[6], b3_bf = s_fl[7];
    const bool out_bf = im_bf && st_bf && w1_bf && w2_bf && w3_bf;

    int p = blockIdx.x;
    int l = (nswz > 0) ? ((p & 7) * nswz + (p >> 3)) : p;
    const int b0 = l * NSAMP;

    unsigned short* su = (unsigned short*)SH;   // halfword view

    // ==== phase 0: waves0-1 = MLP (4 samples each), waves2-7 = image staging ====
    if (wv < 2) {
        int s = wv * 4 + (lane >> 4), j = lane & 15;
        int gi = (b0 + s) * 16 + j;
        s_st[s][j] = st_bf ? bf2f(((const unsigned short*)state)[gi])
                           : ((const float*)state)[gi];
        wsync();
        float acc = b1_bf ? bf2f(((const unsigned short*)b1)[j])
                          : ((const float*)b1)[j];
#pragma unroll
        for (int k = 0; k < 16; ++k) {
            float w = w1_bf ? bf2f(((const unsigned short*)W1)[k * 16 + j])
                            : ((const float*)W1)[k * 16 + j];
            acc += s_st[s][k] * w;
        }
        s_h1[s][j] = fmaxf(acc, 0.f);
        wsync();
        acc = b2_bf ? bf2f(((const unsigned short*)b2)[j])
                    : ((const float*)b2)[j];
#pragma unroll
        for (int k = 0; k < 16; ++k) {
            float w = w2_bf ? bf2f(((const unsigned short*)W2)[k * 16 + j])
                            : ((const float*)W2)[k * 16 + j];
            acc += s_h1[s][k] * w;
        }
        s_h2[s][j] = fmaxf(acc, 0.f);
    } else {
        // staging: prefetch both main loads before unpacking (hide HBM latency)
        int pix0 = t - 128;            // 0..383
        int pix1 = pix0 + 384;         // 384..767
        int pix2 = pix0 + 768;         // 768..1151 (valid only if < 784)
        if (im_bf) {
            const unsigned short* im = (const unsigned short*)image;
            const uint4 v0 = *(const uint4*)(im + pix0 * B + b0);
            const uint4 v1 = *(const uint4*)(im + pix1 * B + b0);
#pragma unroll
            for (int h = 0; h < 2; ++h) {
                const uint4 v = h ? v1 : v0;
                int pix = h ? pix1 : pix0;
                su[0 * 2 * REG + pix] = (unsigned short)(v.x);
                su[1 * 2 * REG + pix] = (unsigned short)(v.x >> 16);
                su[2 * 2 * REG + pix] = (unsigned short)(v.y);
                su[3 * 2 * REG + pix] = (unsigned short)(v.y >> 16);
                su[4 * 2 * REG + pix] = (unsigned short)(v.z);
                su[5 * 2 * REG + pix] = (unsigned short)(v.z >> 16);
                su[6 * 2 * REG + pix] = (unsigned short)(v.w);
                su[7 * 2 * REG + pix] = (unsigned short)(v.w >> 16);
            }
            if (pix2 < 784) {
                const uint4 v = *(const uint4*)(im + pix2 * B + b0);
                su[0 * 2 * REG + pix2] = (unsigned short)(v.x);
                su[1 * 2 * REG + pix2] = (unsigned short)(v.x >> 16);
                su[2 * 2 * REG + pix2] = (unsigned short)(v.y);
                su[3 * 2 * REG + pix2] = (unsigned short)(v.y >> 16);
                su[4 * 2 * REG + pix2] = (unsigned short)(v.z);
                su[5 * 2 * REG + pix2] = (unsigned short)(v.z >> 16);
                su[6 * 2 * REG + pix2] = (unsigned short)(v.w);
                su[7 * 2 * REG + pix2] = (unsigned short)(v.w >> 16);
            }
        } else {
            const float* im = (const float*)image;
            for (int pix = pix0; pix < 784; pix += 384) {
                const float4 a = *(const float4*)(im + pix * B + b0);
                const float4 c = *(const float4*)(im + pix * B + b0 + 4);
                su[0 * 2 * REG + pix] = f2bf(a.x);
                su[1 * 2 * REG + pix] = f2bf(a.y);
                su[2 * 2 * REG + pix] = f2bf(a.z);
                su[3 * 2 * REG + pix] = f2bf(a.w);
                su[4 * 2 * REG + pix] = f2bf(c.x);
                su[5 * 2 * REG + pix] = f2bf(c.y);
                su[6 * 2 * REG + pix] = f2bf(c.z);
                su[7 * 2 * REG + pix] = f2bf(c.w);
            }
        }
    }
    __syncthreads();   // barrier #1: image staged + h2 ready

    // ==== head via MFMA: w[8][811] = h2[8][16] @ W3[16][811] + b3 ====
    // A layout (m120): A[m=lane&15][k=(lane>>4)*8+i]; rows m>=8 and k>=16 zero.
    // B layout (symmetric): B[k][n=lane&15]. C/D (m89): col=lane&15, row=kg*4+reg.
    // Store to PERMUTED index wperm(jn).
    {
        const int n  = lane & 15;
        const int kg = lane >> 4;        // 0..3; kg>=2 -> k>=16 -> zero pad
        bf16x8 afrag;
#pragma unroll
        for (int i = 0; i < 8; ++i) afrag[i] = 0;
        if (kg < 2 && n < 8) {
            const int k0 = kg * 8;
#pragma unroll
            for (int i = 0; i < 8; ++i)
                afrag[i] = (short)f2bf(s_h2[n][k0 + i]);
        }
        for (int tile = wv; tile < 51; tile += 8) {
            const int jn = tile * 16 + n;
            bf16x8 bfrag;
#pragma unroll
            for (int i = 0; i < 8; ++i) bfrag[i] = 0;
            if (kg < 2 && jn < 811) {
                const int k0 = kg * 8;
                if (w3_bf) {
                    const unsigned short* q = (const unsigned short*)W3 + k0 * 811 + jn;
#pragma unroll
                    for (int i = 0; i < 8; ++i) bfrag[i] = (short)q[i * 811];
                } else {
                    const float* q = (const float*)W3 + k0 * 811 + jn;
#pragma unroll
                    for (int i = 0; i < 8; ++i) bfrag[i] = (short)f2bf(q[i * 811]);
                }
            }
            f32x4 c = {0.f, 0.f, 0.f, 0.f};
            c = __builtin_amdgcn_mfma_f32_16x16x32_bf16(afrag, bfrag, c, 0, 0, 0);
            const int row0 = kg * 4;     // rows row0..row0+3
            if (row0 < 8 && jn < 811) {
                float bb = b3_bf ? bf2f(((const unsigned short*)b3)[jn])
                                 : ((const float*)b3)[jn];
                const int pj = wperm(jn);
#pragma unroll
                for (int r = 0; r < 4; ++r)
                    SH[(row0 + r) * REG + OFF_W + pj] = c[r] + bb;
            }
        }
    }
    __syncthreads();   // barrier #2: weights ready — conv phase is wave-local

    // ==== per-wave CNN: wave wv owns sample b0+wv ====
    const int sb  = wv * REG;        // dword base
    const int sb2 = wv * 2 * REG;    // halfword base

    // ---- conv1 (1->3, 28x28 -> fused pool -> 13x13x3 bf16) ----
    {
        float wc[27], cb[3];
#pragma unroll
        for (int i = 0; i < 27; ++i) wc[i] = SH[sb + OFF_W + i];
#pragma unroll
        for (int c = 0; c < 3; ++c) cb[c] = SH[sb + OFF_W + 27 + c];
        const unsigned* suw = (const unsigned*)&SH[sb];  // 2 pixels per dword
#pragma unroll
        for (int it = 0; it < 3; ++it) {
            int pix = lane + it * 64;
            if (pix < 169) {
                int py = pix / 13, px = pix - py * 13;
                int iy = 2 * py;
                float pt[4][4];
#pragma unroll
                for (int dy = 0; dy < 4; ++dy) {
                    int r = (iy + dy) * 14 + px;
                    unsigned d0 = suw[r], d1 = suw[r + 1];
                    pt[dy][0] = __uint_as_float(d0 << 16);
                    pt[dy][1] = __uint_as_float(d0 & 0xffff0000u);
                    pt[dy][2] = __uint_as_float(d1 << 16);
                    pt[dy][3] = __uint_as_float(d1 & 0xffff0000u);
                }
                unsigned short* op = &su[sb2 + HW_P1 + py * 14 + px];
#pragma unroll
                for (int c = 0; c < 3; ++c) {
                    float a00 = 0.f, a01 = 0.f, a10 = 0.f, a11 = 0.f;
#pragma unroll
                    for (int ky = 0; ky < 3; ++ky)
#pragma unroll
                        for (int kx = 0; kx < 3; ++kx) {
                            float w = wc[c * 9 + ky * 3 + kx];
                            a00 += pt[ky][kx] * w;
                            a01 += pt[ky][kx + 1] * w;
                            a10 += pt[ky + 1][kx] * w;
                            a11 += pt[ky + 1][kx + 1] * w;
                        }
                    float m = fmaxf(fmaxf(a00, a01), fmaxf(a10, a11));
                    op[c * 182] = f2bf(fmaxf(m + cb[c], 0.f));
                }
            }
        }
    }
    wsync();

    // ---- conv2 (3->6, 13x13 -> fused pool -> 5x5x6 fp32), ci-outer ----
    // w2 stored [c][ci][tap] -> 9 contiguous weight dwords per (c,ci)
    {
        int g = lane >> 5, q = lane & 31;
        if (q < 25) {
            int py = q / 5, px = q - py * 5;
            const unsigned* p1w = (const unsigned*)&SH[sb + DW_P1];
            float acc[3][4];
#pragma unroll
            for (int it = 0; it < 3; ++it)
#pragma unroll
                for (int i = 0; i < 4; ++i) acc[it][i] = 0.f;
#pragma unroll
            for (int ci = 0; ci < 3; ++ci) {
                float pt[4][4];
#pragma unroll
                for (int dy = 0; dy < 4; ++dy) {
                    int r = ci * 91 + (2 * py + dy) * 7 + px;
                    unsigned d0 = p1w[r], d1 = p1w[r + 1];
                    pt[dy][0] = __uint_as_float(d0 << 16);
                    pt[dy][1] = __uint_as_float(d0 & 0xffff0000u);
                    pt[dy][2] = __uint_as_float(d1 << 16);
                    pt[dy][3] = __uint_as_float(d1 & 0xffff0000u);
                }
#pragma unroll
                for (int it = 0; it < 3; ++it) {
                    int c = it * 2 + g;
                    const int wo = sb + OFF_W + 30 + c * 27 + ci * 9;
                    float wr[9];
#pragma unroll
                    for (int i = 0; i < 9; ++i) wr[i] = SH[wo + i];
#pragma unroll
                    for (int ky = 0; ky < 3; ++ky)
#pragma unroll
                        for (int kx = 0; kx < 3; ++kx) {
                            float w = wr[ky * 3 + kx];
                            acc[it][0] += pt[ky][kx] * w;
                            acc[it][1] += pt[ky][kx + 1] * w;
                            acc[it][2] += pt[ky + 1][kx] * w;
                            acc[it][3] += pt[ky + 1][kx + 1] * w;
                        }
                }
            }
#pragma unroll
            for (int it = 0; it < 3; ++it) {
                int c = it * 2 + g;
                float m = fmaxf(fmaxf(acc[it][0], acc[it][1]),
                                fmaxf(acc[it][2], acc[it][3]));
                SH[sb + OFF_P2 + c * 25 + q] =
                    fmaxf(m + SH[sb + OFF_W + 192 + c], 0.f);
            }
        }
    }
    wsync();

    // ---- conv3 (6->3, 5x5 -> 3x3) + relu, 54-lane split over ci halves ----
    // w3 stored [c][ci][tap] -> 9 contiguous weight dwords per (c,ci);
    // P2 reads 3-contiguous per (ci,ky).
    {
        float acc = 0.f;
        int pq = lane % 27;            // 0..26: c*9 + pos
        int half = lane / 27;          // 0,1 active; lane>=54 idle
        int c = pq / 9, pos = pq - c * 9;
        int py = pos / 3, px = pos - py * 3;
        if (lane < 54) {
            const int cb3 = half * 3;
#pragma unroll
            for (int ci3 = 0; ci3 < 3; ++ci3) {
                const int ci = cb3 + ci3;
                const int wo = sb + OFF_W + 198 + c * 54 + ci * 9;
                float wr[9];
#pragma unroll
                for (int i = 0; i < 9; ++i) wr[i] = SH[wo + i];
                const int pbase = sb + OFF_P2 + ci * 25 + py * 5 + px;
#pragma unroll
                for (int ky = 0; ky < 3; ++ky)
#pragma unroll
                    for (int kx = 0; kx < 3; ++kx)
                        acc += SH[pbase + ky * 5 + kx] * wr[ky * 3 + kx];
            }
        }
        float other = __shfl(acc, (lane + 27) & 63);
        if (lane < 27)
            SH[sb + OFF_P3 + pq] =
                fmaxf(acc + other + SH[sb + OFF_W + 360 + c], 0.f);
    }
    wsync();

    // ---- conv4 (3->16) + bias + residual -> out, 32-lane split over pp ----
    // P3 channel-major (ci*9+pp), w4 spatial-major (pp*3+ci) — unpermuted:
    // the pp,ci loop already walks wo+0..26 contiguously.
    {
        float acc = 0.f;
        int os = lane & 15, h = (lane >> 4) & 1;
        if (lane < 32) {
            const int wo = sb + OFF_W + 363 + os * 27;
            int p0 = h ? 4 : 0, p1 = h ? 9 : 4;
            for (int pp = p0; pp < p1; ++pp)
#pragma unroll
                for (int ci = 0; ci < 3; ++ci)
                    acc += SH[sb + OFF_P3 + ci * 9 + pp] * SH[wo + pp * 3 + ci];
        }
        float other = __shfl(acc, (lane + 16) & 63);
        if (lane < 16) {
            float tot = acc + other + SH[sb + OFF_W + 795 + os] + s_st[wv][os];
            int gi = (b0 + wv) * 16 + os;
            if (out_bf) ((unsigned short*)out)[gi] = f2bf(tot);
            else        ((float*)out)[gi] = tot;
        }
    }
}

extern "C" void kernel_launch(void* const* d_in, const int* in_sizes, int n_in,
                              void* d_out, int out_size, void* d_ws, size_t ws_size,
                              hipStream_t stream) {
    (void)d_ws; (void)ws_size; (void)n_in; (void)out_size;
    int B = in_sizes[1] / 16;              // 16384
    int nblocks = B / NSAMP;               // 2048
    int nswz = (nblocks % 8 == 0) ? (nblocks / 8) : 0;

    dyncnn4_kernel<<<nblocks, BLK, 0, stream>>>(
        d_in[0], d_in[1], d_in[2], d_in[3], d_in[4], d_in[5], d_in[6], d_in[7],
        d_out, B, nswz);
}